// Round 5
// baseline (366.295 us; speedup 1.0000x reference)
//
#include <hip/hip_runtime.h>
#include <hip/hip_bf16.h>

#define D 128
#define SCAN_CHUNK 1024
#define TE 4096  // edges per partition block

typedef __attribute__((ext_vector_type(8))) short bf16x8;
typedef __attribute__((ext_vector_type(4))) float f32x4;
typedef __attribute__((ext_vector_type(2))) float f32x2;

__device__ __forceinline__ float bf_lo(unsigned u) {
    union { unsigned u; float f; } c; c.u = u << 16; return c.f;
}
__device__ __forceinline__ float bf_hi(unsigned u) {
    union { unsigned u; float f; } c; c.u = u & 0xffff0000u; return c.f;
}

// ---------- edge-index dtype detection (int64 vs int32, on-device) ----------
__device__ __forceinline__ bool ei_is64(const int* ei32) {
    return (ei32[1] | ei32[3] | ei32[5] | ei32[7]) == 0;
}
__device__ __forceinline__ int get_idx(const void* ei, bool is64, long long pos) {
    return is64 ? (int)((const long long*)ei)[pos] : ((const int*)ei)[pos];
}

// ---------- f32 -> bf16 bulk convert ----------
__global__ __launch_bounds__(256) void cvt_bf16_kernel(const float* __restrict__ in,
                                                       __hip_bfloat16* __restrict__ outb,
                                                       long long n) {
    long long i = ((long long)blockIdx.x * 256 + threadIdx.x) * 4;
    if (i + 3 < n) {
        float4 v = *reinterpret_cast<const float4*>(in + i);
        __hip_bfloat16 o[4];
        o[0] = __float2bfloat16(v.x); o[1] = __float2bfloat16(v.y);
        o[2] = __float2bfloat16(v.z); o[3] = __float2bfloat16(v.w);
        *reinterpret_cast<ushort4*>(outb + i) = *reinterpret_cast<ushort4*>(o);
    } else {
        for (; i < n; ++i) outb[i] = __float2bfloat16(in[i]);
    }
}

// ---------- both layers' Wcat[n][256] = [Wl[n][:] | Wr[n][:]] in bf16 ----------
__global__ __launch_bounds__(256) void cvt_w2_kernel(
    const float* __restrict__ Wl1, const float* __restrict__ Wr1,
    const float* __restrict__ Wl2, const float* __restrict__ Wr2,
    __hip_bfloat16* __restrict__ Wc1, __hip_bfloat16* __restrict__ Wc2) {
    int i = blockIdx.x * 256 + threadIdx.x;  // 32768 threads
    const float* Wl = Wl1; const float* Wr = Wr1; __hip_bfloat16* Wc = Wc1;
    if (i >= 16384) { i -= 16384; Wl = Wl2; Wr = Wr2; Wc = Wc2; }
    int c = i >> 7, k = i & 127;
    Wc[c * 256 + k] = __float2bfloat16(Wl[i]);
    Wc[c * 256 + 128 + k] = __float2bfloat16(Wr[i]);
}

// ---------- partition pass 1: per-block LDS histogram over buckets ----------
__global__ __launch_bounds__(256) void part_hist_kernel(const void* __restrict__ ei, int E,
                                                        int NB, int NBLK, int SH,
                                                        int* __restrict__ histT) {
    __shared__ int h[512];
    const int t = threadIdx.x;
    for (int b = t; b < 512; b += 256) h[b] = 0;
    bool is64 = ei_is64((const int*)ei);
    __syncthreads();
    const int base = blockIdx.x * TE;
    for (int i = t; i < TE; i += 256) {
        int e = base + i;
        if (e < E) {
            int d = get_idx(ei, is64, (long long)E + e);
            atomicAdd(&h[d >> SH], 1);
        }
    }
    __syncthreads();
    for (int b = t; b < NB; b += 256) histT[b * NBLK + blockIdx.x] = h[b];
}

// ---------- 2-kernel exclusive scan (scan_add folded into consumers) ----------
__global__ __launch_bounds__(256) void scan_partial_kernel(int* __restrict__ arr, int Ntot,
                                                           int* __restrict__ bsum) {
    __shared__ int s[SCAN_CHUNK];
    int base = blockIdx.x * SCAN_CHUNK;
    for (int j = threadIdx.x; j < SCAN_CHUNK; j += 256) {
        int i = base + j;
        s[j] = (i < Ntot) ? arr[i] : 0;
    }
    __syncthreads();
    if (threadIdx.x == 0) {
        int run = 0;
        for (int j = 0; j < SCAN_CHUNK; ++j) { int t = s[j]; s[j] = run; run += t; }
        bsum[blockIdx.x] = run;
    }
    __syncthreads();
    for (int j = threadIdx.x; j < SCAN_CHUNK; j += 256) {
        int i = base + j;
        if (i < Ntot) arr[i] = s[j];
    }
}

__global__ __launch_bounds__(256) void scan_top_kernel(int* __restrict__ bsum, int nb) {
    __shared__ int s[1024];
    const int t = threadIdx.x;
    for (int j = t; j < nb; j += 256) s[j] = bsum[j];
    __syncthreads();
    if (t == 0) {
        int run = 0;
        for (int j = 0; j < nb; ++j) { int v = s[j]; s[j] = run; run += v; }
    }
    __syncthreads();
    for (int j = t; j < nb; j += 256) bsum[j] = s[j];
}

// ---------- partition pass 2: scatter edges grouped by bucket ----------
__global__ __launch_bounds__(256) void part_scatter_kernel(const void* __restrict__ ei, int E,
                                                           int NB, int NBLK, int SH,
                                                           const int* __restrict__ histT,
                                                           const int* __restrict__ bsum,
                                                           uint2* __restrict__ ebuf) {
    __shared__ int cur[512];
    const int t = threadIdx.x;
    bool is64 = ei_is64((const int*)ei);
    for (int b = t; b < NB; b += 256) {
        int idx = b * NBLK + blockIdx.x;
        cur[b] = histT[idx] + bsum[idx >> 10];
    }
    __syncthreads();
    const int base = blockIdx.x * TE;
    for (int i = t; i < TE; i += 256) {
        int e = base + i;
        if (e < E) {
            int s = get_idx(ei, is64, e);
            int d = get_idx(ei, is64, (long long)E + e);
            int pos = atomicAdd(&cur[d >> SH], 1);
            ebuf[pos] = make_uint2((unsigned)s, (unsigned)d);
        }
    }
}

// ---------- per-bucket CSR: LDS node-histogram + scan, contiguous col writes ----------
__global__ __launch_bounds__(256) void bucket_csr_kernel(const uint2* __restrict__ ebuf,
                                                         const int* __restrict__ histT,
                                                         const int* __restrict__ bsum,
                                                         int NB, int NBLK, int SH, int E,
                                                         int N, int* __restrict__ rs,
                                                         int* __restrict__ col) {
    const int b = blockIdx.x, t = threadIdx.x;
    const int nodes = 1 << SH;  // 256
    __shared__ int h[256];
    __shared__ int cur[256];
    __shared__ int sse[2];
    if (t == 0) {
        int i0 = b * NBLK;
        sse[0] = histT[i0] + bsum[i0 >> 10];
        if (b + 1 < NB) {
            int i1 = (b + 1) * NBLK;
            sse[1] = histT[i1] + bsum[i1 >> 10];
        } else {
            sse[1] = E;
        }
    }
    for (int l = t; l < nodes; l += 256) h[l] = 0;
    __syncthreads();
    const int bstart = sse[0], bend = sse[1];
    const int node0 = b << SH;
    for (int i = bstart + t; i < bend; i += 256) {
        int d = (int)ebuf[i].y;
        atomicAdd(&h[d - node0], 1);
    }
    __syncthreads();
    for (int off = 1; off < nodes; off <<= 1) {
        int v = 0;
        if (t < nodes && t >= off) v = h[t - off];
        __syncthreads();
        if (t < nodes && t >= off) h[t] += v;
        __syncthreads();
    }
    if (t < nodes) {
        int node = node0 + t;
        if (node < N) rs[node] = bstart + h[t];      // end offset
        cur[t] = bstart + (t ? h[t - 1] : 0);        // start offset
    }
    __syncthreads();
    for (int i = bstart + t; i < bend; i += 256) {
        uint2 ed = ebuf[i];
        int pos = atomicAdd(&cur[(int)ed.y - node0], 1);
        col[pos] = (int)ed.x;
    }
}

// ---------- fused aggregate-mean + SAGE MFMA GEMM ----------
// Block = 128 output rows. Phase 1: 16 quarter-waves each aggregate full rows
// (16 lanes x 16B = 256B row per gather) for 8 nodes -> bf16 means in swizzled
// LDS. Phase 2: MFMA with A = [LDS mean | global self], B = Wc, out row-masked.
template <typename OutT>
__global__ __launch_bounds__(256) void sage_fused_kernel(
    const ushort* __restrict__ X,   // features: gather source AND self
    const int* __restrict__ rs, const int* __restrict__ col,
    const ushort* __restrict__ Wc, const float* __restrict__ bias,
    OutT* __restrict__ out, int N) {
    __shared__ uint4 ldsA4[2048];  // 32 KB: 128 rows x 256B, 16B-XOR-swizzled
    char* ldsA = (char*)ldsA4;
    const int t = threadIdx.x;
    const int lane = t & 63, w = t >> 6;
    const int q = lane >> 4, lc = lane & 15;
    const int Q = w * 4 + q;  // quarter-wave id 0..15
    const int mbase = blockIdx.x * 128;

    // ---- phase 1: means for rows mbase..mbase+127 ----
    for (int i = 0; i < 8; ++i) {
        int row = i * 16 + Q;
        int v = mbase + row;
        if (v < N) {
            int start = v ? rs[v - 1] : 0, end = rs[v];
            f32x2 a01 = {0.f, 0.f}, a23 = {0.f, 0.f}, a45 = {0.f, 0.f}, a67 = {0.f, 0.f};
            for (int e = start; e < end; ++e) {
                int s = col[e];
                uint4 dv = *reinterpret_cast<const uint4*>(X + (size_t)s * D + lc * 8);
                a01 += (f32x2){bf_lo(dv.x), bf_hi(dv.x)};
                a23 += (f32x2){bf_lo(dv.y), bf_hi(dv.y)};
                a45 += (f32x2){bf_lo(dv.z), bf_hi(dv.z)};
                a67 += (f32x2){bf_lo(dv.w), bf_hi(dv.w)};
            }
            float inv = (end > start) ? 1.0f / (float)(end - start) : 0.f;
            __hip_bfloat16 o[8];
            o[0] = __float2bfloat16(a01.x * inv); o[1] = __float2bfloat16(a01.y * inv);
            o[2] = __float2bfloat16(a23.x * inv); o[3] = __float2bfloat16(a23.y * inv);
            o[4] = __float2bfloat16(a45.x * inv); o[5] = __float2bfloat16(a45.y * inv);
            o[6] = __float2bfloat16(a67.x * inv); o[7] = __float2bfloat16(a67.y * inv);
            int cb = (lc * 16) ^ ((row & 7) << 4);
            *reinterpret_cast<uint4*>(ldsA + row * 256 + cb) =
                *reinterpret_cast<uint4*>(o);
        }
    }
    __syncthreads();

    // ---- phase 2: MFMA ----
    const int lm = lane & 15;
    const int ksub = (lane >> 4) * 8;

    f32x4 acc[2][8];
#pragma unroll
    for (int j = 0; j < 8; ++j) {
        float bv = bias[j * 16 + lm];
        acc[0][j] = {bv, bv, bv, bv};
        acc[1][j] = {bv, bv, bv, bv};
    }

    int r0 = mbase + w * 32 + lm;      if (r0 >= N) r0 = N - 1;
    int r1 = mbase + w * 32 + 16 + lm; if (r1 >= N) r1 = N - 1;
    const ushort* S0 = X + (size_t)r0 * D + ksub;
    const ushort* S1 = X + (size_t)r1 * D + ksub;
    const ushort* Wp = Wc + (size_t)lm * 256 + ksub;
    const int row0 = w * 32 + lm;            // LDS rows (row0&7 == row1&7)
    const int swz = (row0 & 7) << 4;

#pragma unroll
    for (int s = 0; s < 8; ++s) {
        bf16x8 a0, a1;
        if (s < 4) {
            int cb = (ksub * 2 + s * 64) ^ swz;
            a0 = *reinterpret_cast<const bf16x8*>(ldsA + row0 * 256 + cb);
            a1 = *reinterpret_cast<const bf16x8*>(ldsA + (row0 + 16) * 256 + cb);
        } else {
            a0 = *reinterpret_cast<const bf16x8*>(S0 + (s - 4) * 32);
            a1 = *reinterpret_cast<const bf16x8*>(S1 + (s - 4) * 32);
        }
#pragma unroll
        for (int j = 0; j < 8; ++j) {
            bf16x8 b = *reinterpret_cast<const bf16x8*>(Wp + (size_t)j * 16 * 256 + s * 32);
            acc[0][j] = __builtin_amdgcn_mfma_f32_16x16x32_bf16(a0, b, acc[0][j], 0, 0, 0);
            acc[1][j] = __builtin_amdgcn_mfma_f32_16x16x32_bf16(a1, b, acc[1][j], 0, 0, 0);
        }
    }

    const int rr = (lane >> 4) * 4;
#pragma unroll
    for (int mt = 0; mt < 2; ++mt) {
#pragma unroll
        for (int r = 0; r < 4; ++r) {
            int row = mbase + w * 32 + mt * 16 + rr + r;
            if (row < N) {
#pragma unroll
                for (int j = 0; j < 8; ++j) {
                    float val = acc[mt][j][r];
                    if constexpr (sizeof(OutT) == 2)
                        out[(size_t)row * D + j * 16 + lm] = __float2bfloat16(val);
                    else
                        out[(size_t)row * D + j * 16 + lm] = val;
                }
            }
        }
    }
}

extern "C" void kernel_launch(void* const* d_in, const int* in_sizes, int n_in,
                              void* d_out, int out_size, void* d_ws, size_t ws_size,
                              hipStream_t stream) {
    const float* x   = (const float*)d_in[0];
    const void*  ei  = d_in[1];
    const float* Wl1 = (const float*)d_in[2];
    const float* Wr1 = (const float*)d_in[3];
    const float* b1  = (const float*)d_in[4];
    const float* Wl2 = (const float*)d_in[5];
    const float* Wr2 = (const float*)d_in[6];
    const float* b2  = (const float*)d_in[7];
    float* out = (float*)d_out;

    const int N = in_sizes[0] / D;
    const int E = in_sizes[1] / 2;
    const long long ND = (long long)N * D;

    // bucket shift: keep NB <= 512 (N=100000 -> SH=8, NB=391)
    int SH = 8;
    while (((N + (1 << SH) - 1) >> SH) > 512) ++SH;
    const int NB = (N + (1 << SH) - 1) >> SH;
    const int NBLK = (E + TE - 1) / TE;
    const int Ntot = NB * NBLK;
    const int nb2 = (Ntot + SCAN_CHUNK - 1) / SCAN_CHUNK;  // must be <= 1024

    // ws layout (bf16 = ushort)
    ushort* h1b   = (ushort*)d_ws;                      // N*D
    ushort* Wc1   = h1b + ND;                           // 128*256
    ushort* Wc2   = Wc1 + 128 * 256;                    // 128*256
    int*    rs    = (int*)(Wc2 + 128 * 256);            // N
    int*    col   = rs + N;                             // E
    int*    histT = col + E;                            // NB*NBLK
    int*    bsum  = histT + Ntot;                       // nb2
    uint2*  ebuf  = (uint2*)(bsum + ((nb2 + 1) & ~1));  // E pairs
    // xb lives in d_out's first half (dead before fused-2 overwrites d_out)
    ushort* xb = (ushort*)d_out;

    // ---- converts ----
    cvt_bf16_kernel<<<(int)((ND / 4 + 255) / 256), 256, 0, stream>>>(
        x, (__hip_bfloat16*)xb, ND);
    cvt_w2_kernel<<<128, 256, 0, stream>>>(Wl1, Wr1, Wl2, Wr2,
                                           (__hip_bfloat16*)Wc1, (__hip_bfloat16*)Wc2);

    // ---- build CSR via two-level counting sort (LDS atomics only) ----
    part_hist_kernel<<<NBLK, 256, 0, stream>>>(ei, E, NB, NBLK, SH, histT);
    scan_partial_kernel<<<nb2, 256, 0, stream>>>(histT, Ntot, bsum);
    scan_top_kernel<<<1, 256, 0, stream>>>(bsum, nb2);
    part_scatter_kernel<<<NBLK, 256, 0, stream>>>(ei, E, NB, NBLK, SH, histT, bsum, ebuf);
    bucket_csr_kernel<<<NB, 256, 0, stream>>>(ebuf, histT, bsum, NB, NBLK, SH, E, N, rs, col);

    const int fgrid = (N + 127) / 128;

    // ---- layer 1: fused aggregate+GEMM -> h1b (bf16) ----
    sage_fused_kernel<__hip_bfloat16><<<fgrid, 256, 0, stream>>>(
        xb, rs, col, Wc1, b1, (__hip_bfloat16*)h1b, N);

    // ---- layer 2: fused aggregate+GEMM -> out (f32) ----
    sage_fused_kernel<float><<<fgrid, 256, 0, stream>>>(
        h1b, rs, col, Wc2, b2, out, N);
}

// Round 6
// 272.157 us; speedup vs baseline: 1.3459x; 1.3459x over previous
//
#include <hip/hip_runtime.h>
#include <hip/hip_bf16.h>

#define D 128
#define SCAN_CHUNK 1024
#define TE 4096  // edges per partition block

typedef __attribute__((ext_vector_type(8))) short bf16x8;
typedef __attribute__((ext_vector_type(4))) float f32x4;
typedef __attribute__((ext_vector_type(2))) float f32x2;

__device__ __forceinline__ float bf_lo(unsigned u) {
    union { unsigned u; float f; } c; c.u = u << 16; return c.f;
}
__device__ __forceinline__ float bf_hi(unsigned u) {
    union { unsigned u; float f; } c; c.u = u & 0xffff0000u; return c.f;
}

// ---------- edge-index dtype detection (int64 vs int32, on-device) ----------
__device__ __forceinline__ bool ei_is64(const int* ei32) {
    return (ei32[1] | ei32[3] | ei32[5] | ei32[7]) == 0;
}
__device__ __forceinline__ int get_idx(const void* ei, bool is64, long long pos) {
    return is64 ? (int)((const long long*)ei)[pos] : ((const int*)ei)[pos];
}

// ---------- prep: x->bf16 convert | weight converts | partition histogram ----------
// One kernel, branch by blockIdx range (saves 2 launch gaps).
__global__ __launch_bounds__(256) void prep_kernel(
    const float* __restrict__ x, __hip_bfloat16* __restrict__ xb, long long ND,
    int ncvt,
    const float* __restrict__ Wl1, const float* __restrict__ Wr1,
    const float* __restrict__ Wl2, const float* __restrict__ Wr2,
    __hip_bfloat16* __restrict__ Wc1, __hip_bfloat16* __restrict__ Wc2,
    const void* __restrict__ ei, int E, int NB, int NBLK, int SH,
    int* __restrict__ histT) {
    __shared__ int h[512];
    const int t = threadIdx.x;
    int bid = blockIdx.x;

    if (bid < ncvt) {
        long long i = ((long long)bid * 256 + t) * 4;
        if (i + 3 < ND) {
            float4 v = *reinterpret_cast<const float4*>(x + i);
            __hip_bfloat16 o[4];
            o[0] = __float2bfloat16(v.x); o[1] = __float2bfloat16(v.y);
            o[2] = __float2bfloat16(v.z); o[3] = __float2bfloat16(v.w);
            *reinterpret_cast<ushort4*>(xb + i) = *reinterpret_cast<ushort4*>(o);
        } else {
            for (; i < ND; ++i) xb[i] = __float2bfloat16(x[i]);
        }
        return;
    }
    bid -= ncvt;
    if (bid < 128) {
        int i = bid * 256 + t;  // 32768 threads over 2x 16384 weights
        const float* Wl = Wl1; const float* Wr = Wr1; __hip_bfloat16* Wc = Wc1;
        if (i >= 16384) { i -= 16384; Wl = Wl2; Wr = Wr2; Wc = Wc2; }
        int c = i >> 7, k = i & 127;
        Wc[c * 256 + k] = __float2bfloat16(Wl[i]);
        Wc[c * 256 + 128 + k] = __float2bfloat16(Wr[i]);
        return;
    }
    bid -= 128;
    // partition histogram over buckets for edge tile bid
    for (int b = t; b < 512; b += 256) h[b] = 0;
    bool is64 = ei_is64((const int*)ei);
    __syncthreads();
    const int base = bid * TE;
    for (int i = t; i < TE; i += 256) {
        int e = base + i;
        if (e < E) {
            int d = get_idx(ei, is64, (long long)E + e);
            atomicAdd(&h[d >> SH], 1);
        }
    }
    __syncthreads();
    for (int b = t; b < NB; b += 256) histT[b * NBLK + bid] = h[b];
}

// ---------- 2-kernel exclusive scan (scan_add folded into consumers) ----------
__global__ __launch_bounds__(256) void scan_partial_kernel(int* __restrict__ arr, int Ntot,
                                                           int* __restrict__ bsum) {
    __shared__ int s[SCAN_CHUNK];
    int base = blockIdx.x * SCAN_CHUNK;
    for (int j = threadIdx.x; j < SCAN_CHUNK; j += 256) {
        int i = base + j;
        s[j] = (i < Ntot) ? arr[i] : 0;
    }
    __syncthreads();
    if (threadIdx.x == 0) {
        int run = 0;
        for (int j = 0; j < SCAN_CHUNK; ++j) { int t = s[j]; s[j] = run; run += t; }
        bsum[blockIdx.x] = run;
    }
    __syncthreads();
    for (int j = threadIdx.x; j < SCAN_CHUNK; j += 256) {
        int i = base + j;
        if (i < Ntot) arr[i] = s[j];
    }
}

__global__ __launch_bounds__(256) void scan_top_kernel(int* __restrict__ bsum, int nb) {
    __shared__ int s[1024];
    const int t = threadIdx.x;
    for (int j = t; j < nb; j += 256) s[j] = bsum[j];
    __syncthreads();
    if (t == 0) {
        int run = 0;
        for (int j = 0; j < nb; ++j) { int v = s[j]; s[j] = run; run += v; }
    }
    __syncthreads();
    for (int j = t; j < nb; j += 256) bsum[j] = s[j];
}

// ---------- partition pass 2: scatter edges grouped by bucket ----------
// ebuf entry packed: src (24 bits) | local_dst (8 bits) << 24.  Requires
// N < 2^24 and SH <= 8 (holds here: N=100000, SH=8).
__global__ __launch_bounds__(256) void part_scatter_kernel(const void* __restrict__ ei, int E,
                                                           int NB, int NBLK, int SH,
                                                           const int* __restrict__ histT,
                                                           const int* __restrict__ bsum,
                                                           unsigned* __restrict__ ebuf) {
    __shared__ int cur[512];
    const int t = threadIdx.x;
    bool is64 = ei_is64((const int*)ei);
    for (int b = t; b < NB; b += 256) {
        int idx = b * NBLK + blockIdx.x;
        cur[b] = histT[idx] + bsum[idx >> 10];
    }
    __syncthreads();
    const int base = blockIdx.x * TE;
    for (int i = t; i < TE; i += 256) {
        int e = base + i;
        if (e < E) {
            int s = get_idx(ei, is64, e);
            int d = get_idx(ei, is64, (long long)E + e);
            int pos = atomicAdd(&cur[d >> SH], 1);
            ebuf[pos] = (unsigned)s | ((unsigned)(d & ((1 << SH) - 1)) << 24);
        }
    }
}

// ---------- per-bucket CSR: LDS node-histogram + scan, contiguous col writes ----------
__global__ __launch_bounds__(256) void bucket_csr_kernel(const unsigned* __restrict__ ebuf,
                                                         const int* __restrict__ histT,
                                                         const int* __restrict__ bsum,
                                                         int NB, int NBLK, int SH, int E,
                                                         int N, int* __restrict__ rs,
                                                         int* __restrict__ col) {
    const int b = blockIdx.x, t = threadIdx.x;
    const int nodes = 1 << SH;  // 256
    __shared__ int h[256];
    __shared__ int cur[256];
    __shared__ int sse[2];
    if (t == 0) {
        int i0 = b * NBLK;
        sse[0] = histT[i0] + bsum[i0 >> 10];
        if (b + 1 < NB) {
            int i1 = (b + 1) * NBLK;
            sse[1] = histT[i1] + bsum[i1 >> 10];
        } else {
            sse[1] = E;
        }
    }
    for (int l = t; l < nodes; l += 256) h[l] = 0;
    __syncthreads();
    const int bstart = sse[0], bend = sse[1];
    for (int i = bstart + t; i < bend; i += 256) {
        atomicAdd(&h[ebuf[i] >> 24], 1);
    }
    __syncthreads();
    for (int off = 1; off < nodes; off <<= 1) {
        int v = 0;
        if (t < nodes && t >= off) v = h[t - off];
        __syncthreads();
        if (t < nodes && t >= off) h[t] += v;
        __syncthreads();
    }
    const int node0 = b << SH;
    if (t < nodes) {
        int node = node0 + t;
        if (node < N) rs[node] = bstart + h[t];      // end offset
        cur[t] = bstart + (t ? h[t - 1] : 0);        // start offset
    }
    __syncthreads();
    for (int i = bstart + t; i < bend; i += 256) {
        unsigned ed = ebuf[i];
        int pos = atomicAdd(&cur[ed >> 24], 1);
        col[pos] = (int)(ed & 0xFFFFFFu);
    }
}

// ---------- gather-aggregate (mean), bf16 in / bf16 out ----------
// One wave per node; quarter-wave (16 lanes x 16B) covers one 256B row, so one
// dwordx4 instruction gathers 4 edges.  2x unrolled (8 loads in flight/wave),
// packed f32x2 accumulate, cross-quarter shfl reduce.
__global__ __launch_bounds__(256) void aggregate_mean_kernel(
    const ushort* __restrict__ xb, const int* __restrict__ rs,
    const int* __restrict__ col, ushort* __restrict__ outm, int N) {
    int t = threadIdx.x;
    int v = blockIdx.x * 4 + (t >> 6);
    if (v >= N) return;
    int lane = t & 63, q = lane >> 4, lc = lane & 15;
    int start = v ? rs[v - 1] : 0, end = rs[v];
    f32x2 a0 = {0.f, 0.f}, a1 = {0.f, 0.f}, a2 = {0.f, 0.f}, a3 = {0.f, 0.f};
    int e = start + q;
    for (; e + 4 < end; e += 8) {
        int s0 = col[e], s1 = col[e + 4];
        uint4 d0 = *reinterpret_cast<const uint4*>(xb + (size_t)s0 * D + lc * 8);
        uint4 d1 = *reinterpret_cast<const uint4*>(xb + (size_t)s1 * D + lc * 8);
        a0 += (f32x2){bf_lo(d0.x), bf_hi(d0.x)};
        a1 += (f32x2){bf_lo(d0.y), bf_hi(d0.y)};
        a2 += (f32x2){bf_lo(d0.z), bf_hi(d0.z)};
        a3 += (f32x2){bf_lo(d0.w), bf_hi(d0.w)};
        a0 += (f32x2){bf_lo(d1.x), bf_hi(d1.x)};
        a1 += (f32x2){bf_lo(d1.y), bf_hi(d1.y)};
        a2 += (f32x2){bf_lo(d1.z), bf_hi(d1.z)};
        a3 += (f32x2){bf_lo(d1.w), bf_hi(d1.w)};
    }
    if (e < end) {
        int s0 = col[e];
        uint4 d0 = *reinterpret_cast<const uint4*>(xb + (size_t)s0 * D + lc * 8);
        a0 += (f32x2){bf_lo(d0.x), bf_hi(d0.x)};
        a1 += (f32x2){bf_lo(d0.y), bf_hi(d0.y)};
        a2 += (f32x2){bf_lo(d0.z), bf_hi(d0.z)};
        a3 += (f32x2){bf_lo(d0.w), bf_hi(d0.w)};
    }
    float a[8] = {a0.x, a0.y, a1.x, a1.y, a2.x, a2.y, a3.x, a3.y};
#pragma unroll
    for (int i = 0; i < 8; ++i) {
        a[i] += __shfl_xor(a[i], 16);
        a[i] += __shfl_xor(a[i], 32);
    }
    if (q == 0) {
        float inv = (end > start) ? 1.0f / (float)(end - start) : 0.f;
        __hip_bfloat16 o[8];
#pragma unroll
        for (int i = 0; i < 8; ++i) o[i] = __float2bfloat16(a[i] * inv);
        *reinterpret_cast<uint4*>(outm + (size_t)v * D + lc * 8) =
            *reinterpret_cast<uint4*>(o);
    }
}

// ---------- MFMA GEMM: out[m][n] = bias[n] + sum_k A[m][k] * Wcat[n][k]
//   A = [meanb | selfb] (K=256, bf16), no LDS: all frags are contiguous 16B loads.
//   Block = 2 waves = 64 rows (1563 blocks -> low tail quantization).
template <typename OutT>
__global__ __launch_bounds__(128) void sage_mfma_kernel(
    const ushort* __restrict__ Ab, const ushort* __restrict__ Sb,
    const ushort* __restrict__ Wc, const float* __restrict__ bias,
    OutT* __restrict__ out, int N) {
    const int t = threadIdx.x;
    const int lane = t & 63, w = t >> 6;  // w in 0..1
    const int lm = lane & 15;
    const int ksub = (lane >> 4) * 8;
    const int mbase = blockIdx.x * 64 + w * 32;

    int r0 = mbase + lm;      if (r0 >= N) r0 = N - 1;
    int r1 = mbase + 16 + lm; if (r1 >= N) r1 = N - 1;

    f32x4 acc[2][8];
#pragma unroll
    for (int j = 0; j < 8; ++j) {
        float bv = bias[j * 16 + lm];
        acc[0][j] = {bv, bv, bv, bv};
        acc[1][j] = {bv, bv, bv, bv};
    }

    const ushort* A0 = Ab + (size_t)r0 * D + ksub;
    const ushort* A1 = Ab + (size_t)r1 * D + ksub;
    const ushort* S0 = Sb + (size_t)r0 * D + ksub;
    const ushort* S1 = Sb + (size_t)r1 * D + ksub;
    const ushort* Wp = Wc + (size_t)lm * 256 + ksub;

#pragma unroll
    for (int s = 0; s < 8; ++s) {
        bf16x8 a0, a1;
        if (s < 4) {
            a0 = *reinterpret_cast<const bf16x8*>(A0 + s * 32);
            a1 = *reinterpret_cast<const bf16x8*>(A1 + s * 32);
        } else {
            a0 = *reinterpret_cast<const bf16x8*>(S0 + (s - 4) * 32);
            a1 = *reinterpret_cast<const bf16x8*>(S1 + (s - 4) * 32);
        }
#pragma unroll
        for (int j = 0; j < 8; ++j) {
            bf16x8 b = *reinterpret_cast<const bf16x8*>(Wp + (size_t)j * 16 * 256 + s * 32);
            acc[0][j] = __builtin_amdgcn_mfma_f32_16x16x32_bf16(a0, b, acc[0][j], 0, 0, 0);
            acc[1][j] = __builtin_amdgcn_mfma_f32_16x16x32_bf16(a1, b, acc[1][j], 0, 0, 0);
        }
    }

    const int rr = (lane >> 4) * 4;
#pragma unroll
    for (int mt = 0; mt < 2; ++mt) {
#pragma unroll
        for (int r = 0; r < 4; ++r) {
            int row = mbase + mt * 16 + rr + r;
            if (row < N) {
#pragma unroll
                for (int j = 0; j < 8; ++j) {
                    float val = acc[mt][j][r];
                    if constexpr (sizeof(OutT) == 2)
                        out[(size_t)row * D + j * 16 + lm] = __float2bfloat16(val);
                    else
                        out[(size_t)row * D + j * 16 + lm] = val;
                }
            }
        }
    }
}

extern "C" void kernel_launch(void* const* d_in, const int* in_sizes, int n_in,
                              void* d_out, int out_size, void* d_ws, size_t ws_size,
                              hipStream_t stream) {
    const float* x   = (const float*)d_in[0];
    const void*  ei  = d_in[1];
    const float* Wl1 = (const float*)d_in[2];
    const float* Wr1 = (const float*)d_in[3];
    const float* b1  = (const float*)d_in[4];
    const float* Wl2 = (const float*)d_in[5];
    const float* Wr2 = (const float*)d_in[6];
    const float* b2  = (const float*)d_in[7];
    float* out = (float*)d_out;

    const int N = in_sizes[0] / D;
    const int E = in_sizes[1] / 2;
    const long long ND = (long long)N * D;

    // bucket shift: keep NB <= 512 (N=100000 -> SH=8, NB=391)
    int SH = 8;
    while (((N + (1 << SH) - 1) >> SH) > 512) ++SH;
    const int NB = (N + (1 << SH) - 1) >> SH;
    const int NBLK = (E + TE - 1) / TE;
    const int Ntot = NB * NBLK;
    const int nb2 = (Ntot + SCAN_CHUNK - 1) / SCAN_CHUNK;  // must be <= 1024

    // ws layout (bf16 = ushort)
    ushort* meanb = (ushort*)d_ws;                      // N*D
    ushort* h1b   = meanb + ND;                         // N*D
    ushort* Wc1   = h1b + ND;                           // 128*256
    ushort* Wc2   = Wc1 + 128 * 256;                    // 128*256
    int*    rs    = (int*)(Wc2 + 128 * 256);            // N
    int*    col   = rs + N;                             // E
    // transient aliases (dead before their hosts are written):
    int*      histT = (int*)meanb;                      // NB*NBLK (meanb written later)
    int*      bsum  = histT + Ntot;                     // nb2
    unsigned* ebuf  = (unsigned*)h1b;                   // E packed (h1b written later)
    // xb lives in d_out's first half (dead before GEMM2 overwrites d_out)
    ushort* xb = (ushort*)d_out;

    const int ncvt = (int)((ND / 4 + 255) / 256);

    // ---- prep: converts + partition histogram (one kernel) ----
    prep_kernel<<<ncvt + 128 + NBLK, 256, 0, stream>>>(
        x, (__hip_bfloat16*)xb, ND, ncvt, Wl1, Wr1, Wl2, Wr2,
        (__hip_bfloat16*)Wc1, (__hip_bfloat16*)Wc2, ei, E, NB, NBLK, SH, histT);

    // ---- CSR via two-level counting sort (LDS atomics only) ----
    scan_partial_kernel<<<nb2, 256, 0, stream>>>(histT, Ntot, bsum);
    scan_top_kernel<<<1, 256, 0, stream>>>(bsum, nb2);
    part_scatter_kernel<<<NBLK, 256, 0, stream>>>(ei, E, NB, NBLK, SH, histT, bsum, ebuf);
    bucket_csr_kernel<<<NB, 256, 0, stream>>>(ebuf, histT, bsum, NB, NBLK, SH, E, N, rs, col);

    const int agg_grid = (N + 3) / 4;
    const int gemm_grid = (N + 63) / 64;

    // ---- layer 1 ----
    aggregate_mean_kernel<<<agg_grid, 256, 0, stream>>>(xb, rs, col, meanb, N);
    sage_mfma_kernel<__hip_bfloat16><<<gemm_grid, 128, 0, stream>>>(
        meanb, xb, Wc1, b1, (__hip_bfloat16*)h1b, N);

    // ---- layer 2 ----
    aggregate_mean_kernel<<<agg_grid, 256, 0, stream>>>(h1b, rs, col, meanb, N);
    sage_mfma_kernel<float><<<gemm_grid, 128, 0, stream>>>(
        meanb, h1b, Wc2, b2, out, N);
}

// Round 7
// 252.586 us; speedup vs baseline: 1.4502x; 1.0775x over previous
//
#include <hip/hip_runtime.h>
#include <hip/hip_bf16.h>

#define D 128
#define SCAN_CHUNK 1024
#define TE 4096  // edges per partition block

typedef __attribute__((ext_vector_type(8))) short bf16x8;
typedef __attribute__((ext_vector_type(4))) float f32x4;
typedef __attribute__((ext_vector_type(2))) float f32x2;

// ---------- edge-index dtype detection (int64 vs int32, on-device) ----------
__device__ __forceinline__ bool ei_is64(const int* ei32) {
    return (ei32[1] | ei32[3] | ei32[5] | ei32[7]) == 0;
}
__device__ __forceinline__ int get_idx(const void* ei, bool is64, long long pos) {
    return is64 ? (int)((const long long*)ei)[pos] : ((const int*)ei)[pos];
}

// ---------- prep: x->(bf16,fp8) | weight converts | partition histogram ----------
__global__ __launch_bounds__(256) void prep_kernel(
    const float* __restrict__ x, __hip_bfloat16* __restrict__ xb,
    unsigned* __restrict__ xq, long long ND, int ncvt,
    const float* __restrict__ Wl1, const float* __restrict__ Wr1,
    const float* __restrict__ Wl2, const float* __restrict__ Wr2,
    __hip_bfloat16* __restrict__ Wc1, __hip_bfloat16* __restrict__ Wc2,
    const void* __restrict__ ei, int E, int NB, int NBLK, int SH,
    int* __restrict__ histT) {
    __shared__ int h[512];
    const int t = threadIdx.x;
    int bid = blockIdx.x;

    if (bid < ncvt) {
        long long i = ((long long)bid * 256 + t) * 4;
        if (i + 3 < ND) {
            float4 v = *reinterpret_cast<const float4*>(x + i);
            __hip_bfloat16 o[4];
            o[0] = __float2bfloat16(v.x); o[1] = __float2bfloat16(v.y);
            o[2] = __float2bfloat16(v.z); o[3] = __float2bfloat16(v.w);
            *reinterpret_cast<ushort4*>(xb + i) = *reinterpret_cast<ushort4*>(o);
            int pk = __builtin_amdgcn_cvt_pk_fp8_f32(v.x, v.y, 0, false);
            pk = __builtin_amdgcn_cvt_pk_fp8_f32(v.z, v.w, pk, true);
            xq[i >> 2] = (unsigned)pk;
        } else {
            for (; i < ND; ++i) {
                float v = x[i];
                xb[i] = __float2bfloat16(v);
                // tail <4 elems: write fp8 bytes individually
                int pk = __builtin_amdgcn_cvt_pk_fp8_f32(v, v, 0, false);
                ((unsigned char*)xq)[i] = (unsigned char)(pk & 0xff);
            }
        }
        return;
    }
    bid -= ncvt;
    if (bid < 128) {
        int i = bid * 256 + t;  // 32768 threads over 2x 16384 weights
        const float* Wl = Wl1; const float* Wr = Wr1; __hip_bfloat16* Wc = Wc1;
        if (i >= 16384) { i -= 16384; Wl = Wl2; Wr = Wr2; Wc = Wc2; }
        int c = i >> 7, k = i & 127;
        Wc[c * 256 + k] = __float2bfloat16(Wl[i]);
        Wc[c * 256 + 128 + k] = __float2bfloat16(Wr[i]);
        return;
    }
    bid -= 128;
    // partition histogram over buckets for edge tile bid
    for (int b = t; b < 512; b += 256) h[b] = 0;
    bool is64 = ei_is64((const int*)ei);
    __syncthreads();
    const int base = bid * TE;
    for (int i = t; i < TE; i += 256) {
        int e = base + i;
        if (e < E) {
            int d = get_idx(ei, is64, (long long)E + e);
            atomicAdd(&h[d >> SH], 1);
        }
    }
    __syncthreads();
    for (int b = t; b < NB; b += 256) histT[b * NBLK + bid] = h[b];
}

// ---------- 2-kernel exclusive scan (scan_add folded into consumers) ----------
__global__ __launch_bounds__(256) void scan_partial_kernel(int* __restrict__ arr, int Ntot,
                                                           int* __restrict__ bsum) {
    __shared__ int s[SCAN_CHUNK];
    int base = blockIdx.x * SCAN_CHUNK;
    for (int j = threadIdx.x; j < SCAN_CHUNK; j += 256) {
        int i = base + j;
        s[j] = (i < Ntot) ? arr[i] : 0;
    }
    __syncthreads();
    if (threadIdx.x == 0) {
        int run = 0;
        for (int j = 0; j < SCAN_CHUNK; ++j) { int t = s[j]; s[j] = run; run += t; }
        bsum[blockIdx.x] = run;
    }
    __syncthreads();
    for (int j = threadIdx.x; j < SCAN_CHUNK; j += 256) {
        int i = base + j;
        if (i < Ntot) arr[i] = s[j];
    }
}

__global__ __launch_bounds__(256) void scan_top_kernel(int* __restrict__ bsum, int nb) {
    __shared__ int s[1024];
    const int t = threadIdx.x;
    for (int j = t; j < nb; j += 256) s[j] = bsum[j];
    __syncthreads();
    if (t == 0) {
        int run = 0;
        for (int j = 0; j < nb; ++j) { int v = s[j]; s[j] = run; run += v; }
    }
    __syncthreads();
    for (int j = t; j < nb; j += 256) bsum[j] = s[j];
}

// ---------- partition pass 2: scatter edges grouped by bucket ----------
// ebuf entry packed: src (24 bits) | local_dst (8 bits) << 24.
__global__ __launch_bounds__(256) void part_scatter_kernel(const void* __restrict__ ei, int E,
                                                           int NB, int NBLK, int SH,
                                                           const int* __restrict__ histT,
                                                           const int* __restrict__ bsum,
                                                           unsigned* __restrict__ ebuf) {
    __shared__ int cur[512];
    const int t = threadIdx.x;
    bool is64 = ei_is64((const int*)ei);
    for (int b = t; b < NB; b += 256) {
        int idx = b * NBLK + blockIdx.x;
        cur[b] = histT[idx] + bsum[idx >> 10];
    }
    __syncthreads();
    const int base = blockIdx.x * TE;
    for (int i = t; i < TE; i += 256) {
        int e = base + i;
        if (e < E) {
            int s = get_idx(ei, is64, e);
            int d = get_idx(ei, is64, (long long)E + e);
            int pos = atomicAdd(&cur[d >> SH], 1);
            ebuf[pos] = (unsigned)s | ((unsigned)(d & ((1 << SH) - 1)) << 24);
        }
    }
}

// ---------- per-bucket CSR: LDS node-histogram + scan, contiguous col writes ----------
__global__ __launch_bounds__(256) void bucket_csr_kernel(const unsigned* __restrict__ ebuf,
                                                         const int* __restrict__ histT,
                                                         const int* __restrict__ bsum,
                                                         int NB, int NBLK, int SH, int E,
                                                         int N, int* __restrict__ rs,
                                                         int* __restrict__ col) {
    const int b = blockIdx.x, t = threadIdx.x;
    const int nodes = 1 << SH;  // 256
    __shared__ int h[256];
    __shared__ int cur[256];
    __shared__ int sse[2];
    if (t == 0) {
        int i0 = b * NBLK;
        sse[0] = histT[i0] + bsum[i0 >> 10];
        if (b + 1 < NB) {
            int i1 = (b + 1) * NBLK;
            sse[1] = histT[i1] + bsum[i1 >> 10];
        } else {
            sse[1] = E;
        }
    }
    for (int l = t; l < nodes; l += 256) h[l] = 0;
    __syncthreads();
    const int bstart = sse[0], bend = sse[1];
    for (int i = bstart + t; i < bend; i += 256) {
        atomicAdd(&h[ebuf[i] >> 24], 1);
    }
    __syncthreads();
    for (int off = 1; off < nodes; off <<= 1) {
        int v = 0;
        if (t < nodes && t >= off) v = h[t - off];
        __syncthreads();
        if (t < nodes && t >= off) h[t] += v;
        __syncthreads();
    }
    const int node0 = b << SH;
    if (t < nodes) {
        int node = node0 + t;
        if (node < N) rs[node] = bstart + h[t];      // end offset
        cur[t] = bstart + (t ? h[t - 1] : 0);        // start offset
    }
    __syncthreads();
    for (int i = bstart + t; i < bend; i += 256) {
        unsigned ed = ebuf[i];
        int pos = atomicAdd(&cur[ed >> 24], 1);
        col[pos] = (int)(ed & 0xFFFFFFu);
    }
}

// ---------- gather-aggregate (mean), fp8 in / bf16 out ----------
// One wave per node; quarter-wave (16 lanes x 8B) covers one 128B fp8 row, so
// one dwordx2 instruction gathers 4 edges; 2x unrolled (8 loads in flight).
// HW fp8->f32 decode (v_cvt_pk_f32_fp8), packed f32 accumulate, shfl reduce.
__global__ __launch_bounds__(256) void aggregate_mean_fp8_kernel(
    const unsigned char* __restrict__ xq, const int* __restrict__ rs,
    const int* __restrict__ col, ushort* __restrict__ outm, int N) {
    int t = threadIdx.x;
    int v = blockIdx.x * 4 + (t >> 6);
    if (v >= N) return;
    int lane = t & 63, q = lane >> 4, lc = lane & 15;
    int start = v ? rs[v - 1] : 0, end = rs[v];
    f32x2 a0 = {0.f, 0.f}, a1 = {0.f, 0.f}, a2 = {0.f, 0.f}, a3 = {0.f, 0.f};
    int e = start + q;
    for (; e + 4 < end; e += 8) {
        int s0 = col[e], s1 = col[e + 4];
        uint2 d0 = *reinterpret_cast<const uint2*>(xq + (size_t)s0 * D + lc * 8);
        uint2 d1 = *reinterpret_cast<const uint2*>(xq + (size_t)s1 * D + lc * 8);
        a0 += __builtin_amdgcn_cvt_pk_f32_fp8((int)d0.x, false);
        a1 += __builtin_amdgcn_cvt_pk_f32_fp8((int)d0.x, true);
        a2 += __builtin_amdgcn_cvt_pk_f32_fp8((int)d0.y, false);
        a3 += __builtin_amdgcn_cvt_pk_f32_fp8((int)d0.y, true);
        a0 += __builtin_amdgcn_cvt_pk_f32_fp8((int)d1.x, false);
        a1 += __builtin_amdgcn_cvt_pk_f32_fp8((int)d1.x, true);
        a2 += __builtin_amdgcn_cvt_pk_f32_fp8((int)d1.y, false);
        a3 += __builtin_amdgcn_cvt_pk_f32_fp8((int)d1.y, true);
    }
    if (e < end) {
        int s0 = col[e];
        uint2 d0 = *reinterpret_cast<const uint2*>(xq + (size_t)s0 * D + lc * 8);
        a0 += __builtin_amdgcn_cvt_pk_f32_fp8((int)d0.x, false);
        a1 += __builtin_amdgcn_cvt_pk_f32_fp8((int)d0.x, true);
        a2 += __builtin_amdgcn_cvt_pk_f32_fp8((int)d0.y, false);
        a3 += __builtin_amdgcn_cvt_pk_f32_fp8((int)d0.y, true);
    }
    float a[8] = {a0.x, a0.y, a1.x, a1.y, a2.x, a2.y, a3.x, a3.y};
#pragma unroll
    for (int i = 0; i < 8; ++i) {
        a[i] += __shfl_xor(a[i], 16);
        a[i] += __shfl_xor(a[i], 32);
    }
    if (q == 0) {
        float inv = (end > start) ? 1.0f / (float)(end - start) : 0.f;
        __hip_bfloat16 o[8];
#pragma unroll
        for (int i = 0; i < 8; ++i) o[i] = __float2bfloat16(a[i] * inv);
        *reinterpret_cast<uint4*>(outm + (size_t)v * D + lc * 8) =
            *reinterpret_cast<uint4*>(o);
    }
}

// ---------- MFMA GEMM: out[m][n] = bias[n] + sum_k A[m][k] * Wcat[n][k]
//   A = [meanb | selfb] (K=256, bf16), no LDS: all frags are contiguous 16B loads.
//   DUAL: additionally emit fp8 copy of the output (for next layer's gather).
template <typename OutT, bool DUAL>
__global__ __launch_bounds__(128) void sage_mfma_kernel(
    const ushort* __restrict__ Ab, const ushort* __restrict__ Sb,
    const ushort* __restrict__ Wc, const float* __restrict__ bias,
    OutT* __restrict__ out, unsigned char* __restrict__ fq, int N) {
    const int t = threadIdx.x;
    const int lane = t & 63, w = t >> 6;  // w in 0..1
    const int lm = lane & 15;
    const int ksub = (lane >> 4) * 8;
    const int mbase = blockIdx.x * 64 + w * 32;

    int r0 = mbase + lm;      if (r0 >= N) r0 = N - 1;
    int r1 = mbase + 16 + lm; if (r1 >= N) r1 = N - 1;

    f32x4 acc[2][8];
#pragma unroll
    for (int j = 0; j < 8; ++j) {
        float bv = bias[j * 16 + lm];
        acc[0][j] = {bv, bv, bv, bv};
        acc[1][j] = {bv, bv, bv, bv};
    }

    const ushort* A0 = Ab + (size_t)r0 * D + ksub;
    const ushort* A1 = Ab + (size_t)r1 * D + ksub;
    const ushort* S0 = Sb + (size_t)r0 * D + ksub;
    const ushort* S1 = Sb + (size_t)r1 * D + ksub;
    const ushort* Wp = Wc + (size_t)lm * 256 + ksub;

#pragma unroll
    for (int s = 0; s < 8; ++s) {
        bf16x8 a0, a1;
        if (s < 4) {
            a0 = *reinterpret_cast<const bf16x8*>(A0 + s * 32);
            a1 = *reinterpret_cast<const bf16x8*>(A1 + s * 32);
        } else {
            a0 = *reinterpret_cast<const bf16x8*>(S0 + (s - 4) * 32);
            a1 = *reinterpret_cast<const bf16x8*>(S1 + (s - 4) * 32);
        }
#pragma unroll
        for (int j = 0; j < 8; ++j) {
            bf16x8 b = *reinterpret_cast<const bf16x8*>(Wp + (size_t)j * 16 * 256 + s * 32);
            acc[0][j] = __builtin_amdgcn_mfma_f32_16x16x32_bf16(a0, b, acc[0][j], 0, 0, 0);
            acc[1][j] = __builtin_amdgcn_mfma_f32_16x16x32_bf16(a1, b, acc[1][j], 0, 0, 0);
        }
    }

    const int rr = (lane >> 4) * 4;
#pragma unroll
    for (int mt = 0; mt < 2; ++mt) {
#pragma unroll
        for (int r = 0; r < 4; ++r) {
            int row = mbase + mt * 16 + rr + r;
            if (row < N) {
#pragma unroll
                for (int j = 0; j < 8; ++j) {
                    float val = acc[mt][j][r];
                    if constexpr (sizeof(OutT) == 2)
                        out[(size_t)row * D + j * 16 + lm] = __float2bfloat16(val);
                    else
                        out[(size_t)row * D + j * 16 + lm] = val;
                    if constexpr (DUAL) {
                        int pk = __builtin_amdgcn_cvt_pk_fp8_f32(val, val, 0, false);
                        fq[(size_t)row * D + j * 16 + lm] = (unsigned char)(pk & 0xff);
                    }
                }
            }
        }
    }
}

extern "C" void kernel_launch(void* const* d_in, const int* in_sizes, int n_in,
                              void* d_out, int out_size, void* d_ws, size_t ws_size,
                              hipStream_t stream) {
    const float* x   = (const float*)d_in[0];
    const void*  ei  = d_in[1];
    const float* Wl1 = (const float*)d_in[2];
    const float* Wr1 = (const float*)d_in[3];
    const float* b1  = (const float*)d_in[4];
    const float* Wl2 = (const float*)d_in[5];
    const float* Wr2 = (const float*)d_in[6];
    const float* b2  = (const float*)d_in[7];
    float* out = (float*)d_out;

    const int N = in_sizes[0] / D;
    const int E = in_sizes[1] / 2;
    const long long ND = (long long)N * D;

    // bucket shift: keep NB <= 512 (N=100000 -> SH=8, NB=391)
    int SH = 8;
    while (((N + (1 << SH) - 1) >> SH) > 512) ++SH;
    const int NB = (N + (1 << SH) - 1) >> SH;
    const int NBLK = (E + TE - 1) / TE;
    const int Ntot = NB * NBLK;
    const int nb2 = (Ntot + SCAN_CHUNK - 1) / SCAN_CHUNK;  // must be <= 1024

    // ws layout (bf16 = ushort)
    ushort* meanb = (ushort*)d_ws;                      // N*D
    ushort* h1b   = meanb + ND;                         // N*D
    ushort* Wc1   = h1b + ND;                           // 128*256
    ushort* Wc2   = Wc1 + 128 * 256;                    // 128*256
    int*    rs    = (int*)(Wc2 + 128 * 256);            // N
    int*    col   = rs + N;                             // E
    // transient aliases (dead before their hosts are written):
    int*      histT = (int*)meanb;                      // NB*NBLK (meanb written later)
    int*      bsum  = histT + Ntot;                     // nb2
    unsigned* ebuf  = (unsigned*)h1b;                   // E packed (h1b written later)
    // d_out carve-up (all dead before GEMM2 writes out):
    //   [0, 2*ND): xb bf16; [2*ND, 3*ND): xq fp8; [3*ND, 4*ND): h1q fp8
    ushort*        xb  = (ushort*)d_out;
    unsigned char* xq  = (unsigned char*)d_out + 2 * ND;
    unsigned char* h1q = (unsigned char*)d_out + 3 * ND;

    const int ncvt = (int)((ND / 4 + 255) / 256);

    // ---- prep: converts + partition histogram (one kernel) ----
    prep_kernel<<<ncvt + 128 + NBLK, 256, 0, stream>>>(
        x, (__hip_bfloat16*)xb, (unsigned*)xq, ND, ncvt, Wl1, Wr1, Wl2, Wr2,
        (__hip_bfloat16*)Wc1, (__hip_bfloat16*)Wc2, ei, E, NB, NBLK, SH, histT);

    // ---- CSR via two-level counting sort (LDS atomics only) ----
    scan_partial_kernel<<<nb2, 256, 0, stream>>>(histT, Ntot, bsum);
    scan_top_kernel<<<1, 256, 0, stream>>>(bsum, nb2);
    part_scatter_kernel<<<NBLK, 256, 0, stream>>>(ei, E, NB, NBLK, SH, histT, bsum, ebuf);
    bucket_csr_kernel<<<NB, 256, 0, stream>>>(ebuf, histT, bsum, NB, NBLK, SH, E, N, rs, col);

    const int agg_grid = (N + 3) / 4;
    const int gemm_grid = (N + 63) / 64;

    // ---- layer 1: gather fp8 x -> mean; GEMM (self bf16) -> h1b + h1q ----
    aggregate_mean_fp8_kernel<<<agg_grid, 256, 0, stream>>>(xq, rs, col, meanb, N);
    sage_mfma_kernel<__hip_bfloat16, true><<<gemm_grid, 128, 0, stream>>>(
        meanb, xb, Wc1, b1, (__hip_bfloat16*)h1b, h1q, N);

    // ---- layer 2: gather fp8 h1 -> mean; GEMM (self bf16) -> out f32 ----
    aggregate_mean_fp8_kernel<<<agg_grid, 256, 0, stream>>>(h1q, rs, col, meanb, N);
    sage_mfma_kernel<float, false><<<gemm_grid, 128, 0, stream>>>(
        meanb, h1b, Wc2, b2, out, nullptr, N);
}

// Round 8
// 200.164 us; speedup vs baseline: 1.8300x; 1.2619x over previous
//
#include <hip/hip_runtime.h>
#include <hip/hip_bf16.h>

#define D 128
#define SCAN_CHUNK 1024
#define TE 4096  // edges per partition block

typedef __attribute__((ext_vector_type(8))) short bf16x8;
typedef __attribute__((ext_vector_type(4))) float f32x4;
typedef __attribute__((ext_vector_type(2))) float f32x2;

// ---------- edge-index dtype detection (int64 vs int32, on-device) ----------
__device__ __forceinline__ bool ei_is64(const int* ei32) {
    return (ei32[1] | ei32[3] | ei32[5] | ei32[7]) == 0;
}
__device__ __forceinline__ int get_idx(const void* ei, bool is64, long long pos) {
    return is64 ? (int)((const long long*)ei)[pos] : ((const int*)ei)[pos];
}

// ---------- prep: x->(bf16,fp8) | frag-major weight build | partition histogram ----
// Wf layout: slot id = (j*8+s)*64 + lane holds the 16B B-fragment for MFMA
// (j = n-tile 0..7, s = k-step 0..7): element c = j*16+(lane&15),
// k8 = s*32+(lane>>4)*8 .. +7 of Wcat[c][0..255] = [Wl row | Wr row].
__global__ __launch_bounds__(256) void prep_kernel(
    const float* __restrict__ x, __hip_bfloat16* __restrict__ xb,
    unsigned* __restrict__ xq, long long ND, int ncvt,
    const float* __restrict__ Wl1, const float* __restrict__ Wr1,
    const float* __restrict__ Wl2, const float* __restrict__ Wr2,
    ushort* __restrict__ Wf1, ushort* __restrict__ Wf2,
    const void* __restrict__ ei, int E, int NB, int NBLK, int SH,
    int* __restrict__ histT) {
    __shared__ int h[512];
    const int t = threadIdx.x;
    int bid = blockIdx.x;

    if (bid < ncvt) {
        long long i = ((long long)bid * 256 + t) * 4;
        if (i + 3 < ND) {
            float4 v = *reinterpret_cast<const float4*>(x + i);
            __hip_bfloat16 o[4];
            o[0] = __float2bfloat16(v.x); o[1] = __float2bfloat16(v.y);
            o[2] = __float2bfloat16(v.z); o[3] = __float2bfloat16(v.w);
            *reinterpret_cast<ushort4*>(xb + i) = *reinterpret_cast<ushort4*>(o);
            int pk = __builtin_amdgcn_cvt_pk_fp8_f32(v.x, v.y, 0, false);
            pk = __builtin_amdgcn_cvt_pk_fp8_f32(v.z, v.w, pk, true);
            xq[i >> 2] = (unsigned)pk;
        } else {
            for (; i < ND; ++i) {
                float v = x[i];
                xb[i] = __float2bfloat16(v);
                int pk = __builtin_amdgcn_cvt_pk_fp8_f32(v, v, 0, false);
                ((unsigned char*)xq)[i] = (unsigned char)(pk & 0xff);
            }
        }
        return;
    }
    bid -= ncvt;
    if (bid < 32) {
        int gid = bid * 256 + t;           // 8192 threads: 2 layers x 4096 slots
        int id = gid & 4095;
        const float* Wl = Wl1; const float* Wr = Wr1; ushort* Wf = Wf1;
        if (gid >= 4096) { Wl = Wl2; Wr = Wr2; Wf = Wf2; }
        int lane = id & 63, s = (id >> 6) & 7, j = id >> 9;
        int c = j * 16 + (lane & 15);
        int k = s * 32 + ((lane >> 4) << 3);  // 8 consecutive k from here
        const float* src = (k < 128) ? (Wl + c * 128 + k) : (Wr + c * 128 + (k - 128));
        float4 v0 = *reinterpret_cast<const float4*>(src);
        float4 v1 = *reinterpret_cast<const float4*>(src + 4);
        __hip_bfloat16 o[8];
        o[0] = __float2bfloat16(v0.x); o[1] = __float2bfloat16(v0.y);
        o[2] = __float2bfloat16(v0.z); o[3] = __float2bfloat16(v0.w);
        o[4] = __float2bfloat16(v1.x); o[5] = __float2bfloat16(v1.y);
        o[6] = __float2bfloat16(v1.z); o[7] = __float2bfloat16(v1.w);
        *reinterpret_cast<uint4*>(Wf + (size_t)id * 8) = *reinterpret_cast<uint4*>(o);
        return;
    }
    bid -= 32;
    // partition histogram over buckets for edge tile bid
    for (int b = t; b < 512; b += 256) h[b] = 0;
    bool is64 = ei_is64((const int*)ei);
    __syncthreads();
    const int base = bid * TE;
    for (int i = t; i < TE; i += 256) {
        int e = base + i;
        if (e < E) {
            int d = get_idx(ei, is64, (long long)E + e);
            atomicAdd(&h[d >> SH], 1);
        }
    }
    __syncthreads();
    for (int b = t; b < NB; b += 256) histT[b * NBLK + bid] = h[b];
}

// ---------- 2-kernel exclusive scan (scan_add folded into consumers) ----------
__global__ __launch_bounds__(256) void scan_partial_kernel(int* __restrict__ arr, int Ntot,
                                                           int* __restrict__ bsum) {
    __shared__ int s[SCAN_CHUNK];
    int base = blockIdx.x * SCAN_CHUNK;
    for (int j = threadIdx.x; j < SCAN_CHUNK; j += 256) {
        int i = base + j;
        s[j] = (i < Ntot) ? arr[i] : 0;
    }
    __syncthreads();
    if (threadIdx.x == 0) {
        int run = 0;
        for (int j = 0; j < SCAN_CHUNK; ++j) { int t = s[j]; s[j] = run; run += t; }
        bsum[blockIdx.x] = run;
    }
    __syncthreads();
    for (int j = threadIdx.x; j < SCAN_CHUNK; j += 256) {
        int i = base + j;
        if (i < Ntot) arr[i] = s[j];
    }
}

__global__ __launch_bounds__(256) void scan_top_kernel(int* __restrict__ bsum, int nb) {
    __shared__ int s[1024];
    const int t = threadIdx.x;
    for (int j = t; j < nb; j += 256) s[j] = bsum[j];
    __syncthreads();
    if (t == 0) {
        int run = 0;
        for (int j = 0; j < nb; ++j) { int v = s[j]; s[j] = run; run += v; }
    }
    __syncthreads();
    for (int j = t; j < nb; j += 256) bsum[j] = s[j];
}

// ---------- partition pass 2: scatter edges grouped by bucket ----------
// ebuf entry packed: src (24 bits) | local_dst (8 bits) << 24.
__global__ __launch_bounds__(256) void part_scatter_kernel(const void* __restrict__ ei, int E,
                                                           int NB, int NBLK, int SH,
                                                           const int* __restrict__ histT,
                                                           const int* __restrict__ bsum,
                                                           unsigned* __restrict__ ebuf) {
    __shared__ int cur[512];
    const int t = threadIdx.x;
    bool is64 = ei_is64((const int*)ei);
    for (int b = t; b < NB; b += 256) {
        int idx = b * NBLK + blockIdx.x;
        cur[b] = histT[idx] + bsum[idx >> 10];
    }
    __syncthreads();
    const int base = blockIdx.x * TE;
    for (int i = t; i < TE; i += 256) {
        int e = base + i;
        if (e < E) {
            int s = get_idx(ei, is64, e);
            int d = get_idx(ei, is64, (long long)E + e);
            int pos = atomicAdd(&cur[d >> SH], 1);
            ebuf[pos] = (unsigned)s | ((unsigned)(d & ((1 << SH) - 1)) << 24);
        }
    }
}

// ---------- per-bucket CSR: LDS node-histogram + scan, contiguous col writes ----------
__global__ __launch_bounds__(256) void bucket_csr_kernel(const unsigned* __restrict__ ebuf,
                                                         const int* __restrict__ histT,
                                                         const int* __restrict__ bsum,
                                                         int NB, int NBLK, int SH, int E,
                                                         int N, int* __restrict__ rs,
                                                         int* __restrict__ col) {
    const int b = blockIdx.x, t = threadIdx.x;
    const int nodes = 1 << SH;  // 256
    __shared__ int h[256];
    __shared__ int cur[256];
    __shared__ int sse[2];
    if (t == 0) {
        int i0 = b * NBLK;
        sse[0] = histT[i0] + bsum[i0 >> 10];
        if (b + 1 < NB) {
            int i1 = (b + 1) * NBLK;
            sse[1] = histT[i1] + bsum[i1 >> 10];
        } else {
            sse[1] = E;
        }
    }
    for (int l = t; l < nodes; l += 256) h[l] = 0;
    __syncthreads();
    const int bstart = sse[0], bend = sse[1];
    for (int i = bstart + t; i < bend; i += 256) {
        atomicAdd(&h[ebuf[i] >> 24], 1);
    }
    __syncthreads();
    for (int off = 1; off < nodes; off <<= 1) {
        int v = 0;
        if (t < nodes && t >= off) v = h[t - off];
        __syncthreads();
        if (t < nodes && t >= off) h[t] += v;
        __syncthreads();
    }
    const int node0 = b << SH;
    if (t < nodes) {
        int node = node0 + t;
        if (node < N) rs[node] = bstart + h[t];      // end offset
        cur[t] = bstart + (t ? h[t - 1] : 0);        // start offset
    }
    __syncthreads();
    for (int i = bstart + t; i < bend; i += 256) {
        unsigned ed = ebuf[i];
        int pos = atomicAdd(&cur[ed >> 24], 1);
        col[pos] = (int)(ed & 0xFFFFFFu);
    }
}

// ---------- gather-aggregate (mean), fp8 in / bf16 out ----------
__global__ __launch_bounds__(256) void aggregate_mean_fp8_kernel(
    const unsigned char* __restrict__ xq, const int* __restrict__ rs,
    const int* __restrict__ col, ushort* __restrict__ outm, int N) {
    int t = threadIdx.x;
    int v = blockIdx.x * 4 + (t >> 6);
    if (v >= N) return;
    int lane = t & 63, q = lane >> 4, lc = lane & 15;
    int start = v ? rs[v - 1] : 0, end = rs[v];
    f32x2 a0 = {0.f, 0.f}, a1 = {0.f, 0.f}, a2 = {0.f, 0.f}, a3 = {0.f, 0.f};
    int e = start + q;
    for (; e + 4 < end; e += 8) {
        int s0 = col[e], s1 = col[e + 4];
        uint2 d0 = *reinterpret_cast<const uint2*>(xq + (size_t)s0 * D + lc * 8);
        uint2 d1 = *reinterpret_cast<const uint2*>(xq + (size_t)s1 * D + lc * 8);
        a0 += __builtin_amdgcn_cvt_pk_f32_fp8((int)d0.x, false);
        a1 += __builtin_amdgcn_cvt_pk_f32_fp8((int)d0.x, true);
        a2 += __builtin_amdgcn_cvt_pk_f32_fp8((int)d0.y, false);
        a3 += __builtin_amdgcn_cvt_pk_f32_fp8((int)d0.y, true);
        a0 += __builtin_amdgcn_cvt_pk_f32_fp8((int)d1.x, false);
        a1 += __builtin_amdgcn_cvt_pk_f32_fp8((int)d1.x, true);
        a2 += __builtin_amdgcn_cvt_pk_f32_fp8((int)d1.y, false);
        a3 += __builtin_amdgcn_cvt_pk_f32_fp8((int)d1.y, true);
    }
    if (e < end) {
        int s0 = col[e];
        uint2 d0 = *reinterpret_cast<const uint2*>(xq + (size_t)s0 * D + lc * 8);
        a0 += __builtin_amdgcn_cvt_pk_f32_fp8((int)d0.x, false);
        a1 += __builtin_amdgcn_cvt_pk_f32_fp8((int)d0.x, true);
        a2 += __builtin_amdgcn_cvt_pk_f32_fp8((int)d0.y, false);
        a3 += __builtin_amdgcn_cvt_pk_f32_fp8((int)d0.y, true);
    }
    float a[8] = {a0.x, a0.y, a1.x, a1.y, a2.x, a2.y, a3.x, a3.y};
#pragma unroll
    for (int i = 0; i < 8; ++i) {
        a[i] += __shfl_xor(a[i], 16);
        a[i] += __shfl_xor(a[i], 32);
    }
    if (q == 0) {
        float inv = (end > start) ? 1.0f / (float)(end - start) : 0.f;
        __hip_bfloat16 o[8];
#pragma unroll
        for (int i = 0; i < 8; ++i) o[i] = __float2bfloat16(a[i] * inv);
        *reinterpret_cast<uint4*>(outm + (size_t)v * D + lc * 8) =
            *reinterpret_cast<uint4*>(o);
    }
}

// ---------- MFMA GEMM, LDS-staged frag-major B ----------
// Block = 512 threads = 8 waves, each wave 1 m-tile (16 rows) -> 128 rows/block.
// B (64 KB, frag-major) staged linearly in LDS; inner reads are ds_read_b128
// at lane*16 + immediate -> conflict-free. A/S frags are 16B global loads.
template <typename OutT, bool DUAL>
__global__ __launch_bounds__(512) void sage_mfma_kernel(
    const ushort* __restrict__ Ab, const ushort* __restrict__ Sb,
    const ushort* __restrict__ Wf, const float* __restrict__ bias,
    OutT* __restrict__ out, unsigned char* __restrict__ fq, int N) {
    __shared__ uint4 ldsB[4096];  // 64 KB
    const int t = threadIdx.x;
    {
        const uint4* g = reinterpret_cast<const uint4*>(Wf);
#pragma unroll
        for (int i = 0; i < 8; ++i) ldsB[t + i * 512] = g[t + i * 512];
    }
    __syncthreads();

    const int lane = t & 63, w = t >> 6;
    const int lm = lane & 15;
    const int ksub = (lane >> 4) * 8;
    const int mbase = blockIdx.x * 128 + w * 16;

    int r0 = mbase + lm;
    if (r0 >= N) r0 = N - 1;

    f32x4 acc[8];
#pragma unroll
    for (int j = 0; j < 8; ++j) {
        float bv = bias[j * 16 + lm];
        acc[j] = {bv, bv, bv, bv};
    }

    const ushort* A0 = Ab + (size_t)r0 * D + ksub;
    const ushort* S0 = Sb + (size_t)r0 * D + ksub;
    const ushort* lB = reinterpret_cast<const ushort*>(ldsB) + lane * 8;

#pragma unroll
    for (int s = 0; s < 8; ++s) {
        bf16x8 a = (s < 4) ? *reinterpret_cast<const bf16x8*>(A0 + s * 32)
                           : *reinterpret_cast<const bf16x8*>(S0 + (s - 4) * 32);
#pragma unroll
        for (int j = 0; j < 8; ++j) {
            bf16x8 b = *reinterpret_cast<const bf16x8*>(lB + (j * 8 + s) * 512);
            acc[j] = __builtin_amdgcn_mfma_f32_16x16x32_bf16(a, b, acc[j], 0, 0, 0);
        }
    }

    const int rr = (lane >> 4) * 4;
#pragma unroll
    for (int r = 0; r < 4; ++r) {
        int row = mbase + rr + r;
        if (row < N) {
#pragma unroll
            for (int j = 0; j < 8; ++j) {
                float val = acc[j][r];
                if constexpr (sizeof(OutT) == 2)
                    out[(size_t)row * D + j * 16 + lm] = __float2bfloat16(val);
                else
                    out[(size_t)row * D + j * 16 + lm] = val;
                if constexpr (DUAL) {
                    int pk = __builtin_amdgcn_cvt_pk_fp8_f32(val, val, 0, false);
                    fq[(size_t)row * D + j * 16 + lm] = (unsigned char)(pk & 0xff);
                }
            }
        }
    }
}

extern "C" void kernel_launch(void* const* d_in, const int* in_sizes, int n_in,
                              void* d_out, int out_size, void* d_ws, size_t ws_size,
                              hipStream_t stream) {
    const float* x   = (const float*)d_in[0];
    const void*  ei  = d_in[1];
    const float* Wl1 = (const float*)d_in[2];
    const float* Wr1 = (const float*)d_in[3];
    const float* b1  = (const float*)d_in[4];
    const float* Wl2 = (const float*)d_in[5];
    const float* Wr2 = (const float*)d_in[6];
    const float* b2  = (const float*)d_in[7];
    float* out = (float*)d_out;

    const int N = in_sizes[0] / D;
    const int E = in_sizes[1] / 2;
    const long long ND = (long long)N * D;

    // bucket shift: keep NB <= 512 (N=100000 -> SH=8, NB=391)
    int SH = 8;
    while (((N + (1 << SH) - 1) >> SH) > 512) ++SH;
    const int NB = (N + (1 << SH) - 1) >> SH;
    const int NBLK = (E + TE - 1) / TE;
    const int Ntot = NB * NBLK;
    const int nb2 = (Ntot + SCAN_CHUNK - 1) / SCAN_CHUNK;  // must be <= 1024

    // ws layout (bf16 = ushort)
    ushort* meanb = (ushort*)d_ws;                      // N*D
    ushort* h1b   = meanb + ND;                         // N*D
    ushort* Wf1   = h1b + ND;                           // 4096*8
    ushort* Wf2   = Wf1 + 32768;                        // 4096*8
    int*    rs    = (int*)(Wf2 + 32768);                // N
    int*    col   = rs + N;                             // E
    // transient aliases (dead before their hosts are written):
    int*      histT = (int*)meanb;                      // NB*NBLK (meanb written later)
    int*      bsum  = histT + Ntot;                     // nb2
    unsigned* ebuf  = (unsigned*)h1b;                   // E packed (h1b written later)
    // d_out carve-up (all dead before GEMM2 writes out):
    //   [0, 2*ND): xb bf16; [2*ND, 3*ND): xq fp8; [3*ND, 4*ND): h1q fp8
    ushort*        xb  = (ushort*)d_out;
    unsigned char* xq  = (unsigned char*)d_out + 2 * ND;
    unsigned char* h1q = (unsigned char*)d_out + 3 * ND;

    const int ncvt = (int)((ND / 4 + 255) / 256);

    // ---- prep: converts + frag-major weights + partition histogram ----
    prep_kernel<<<ncvt + 32 + NBLK, 256, 0, stream>>>(
        x, (__hip_bfloat16*)xb, (unsigned*)xq, ND, ncvt, Wl1, Wr1, Wl2, Wr2,
        Wf1, Wf2, ei, E, NB, NBLK, SH, histT);

    // ---- CSR via two-level counting sort (LDS atomics only) ----
    scan_partial_kernel<<<nb2, 256, 0, stream>>>(histT, Ntot, bsum);
    scan_top_kernel<<<1, 256, 0, stream>>>(bsum, nb2);
    part_scatter_kernel<<<NBLK, 256, 0, stream>>>(ei, E, NB, NBLK, SH, histT, bsum, ebuf);
    bucket_csr_kernel<<<NB, 256, 0, stream>>>(ebuf, histT, bsum, NB, NBLK, SH, E, N, rs, col);

    const int agg_grid = (N + 3) / 4;
    const int gemm_grid = (N + 127) / 128;

    // ---- layer 1: gather fp8 x -> mean; GEMM (self bf16) -> h1b + h1q ----
    aggregate_mean_fp8_kernel<<<agg_grid, 256, 0, stream>>>(xq, rs, col, meanb, N);
    sage_mfma_kernel<__hip_bfloat16, true><<<gemm_grid, 512, 0, stream>>>(
        meanb, xb, Wf1, b1, (__hip_bfloat16*)h1b, h1q, N);

    // ---- layer 2: gather fp8 h1 -> mean; GEMM (self bf16) -> out f32 ----
    aggregate_mean_fp8_kernel<<<agg_grid, 256, 0, stream>>>(h1q, rs, col, meanb, N);
    sage_mfma_kernel<float, false><<<gemm_grid, 512, 0, stream>>>(
        meanb, h1b, Wf2, b2, out, nullptr, N);
}

// Round 9
// 180.199 us; speedup vs baseline: 2.0327x; 1.1108x over previous
//
#include <hip/hip_runtime.h>
#include <hip/hip_bf16.h>

#define D 128
#define SCAN_CHUNK 1024
#define TE 4096  // edges per partition block

typedef __attribute__((ext_vector_type(8))) short bf16x8;
typedef __attribute__((ext_vector_type(4))) float f32x4;
typedef __attribute__((ext_vector_type(2))) float f32x2;

// ---------- edge-index dtype detection (int64 vs int32, on-device) ----------
__device__ __forceinline__ bool ei_is64(const int* ei32) {
    return (ei32[1] | ei32[3] | ei32[5] | ei32[7]) == 0;
}
__device__ __forceinline__ int get_idx(const void* ei, bool is64, long long pos) {
    return is64 ? (int)((const long long*)ei)[pos] : ((const int*)ei)[pos];
}

// ---------- prep: x->fp8 | frag-major weight build | partition histogram ----------
// Wf layout: slot id = (j*8+s)*64 + lane holds the 16B B-fragment for MFMA
// (j = n-tile 0..7, s = k-step 0..7): element c = j*16+(lane&15),
// k8 = s*32+(lane>>4)*8 .. +7 of Wcat[c][0..255] = [Wl row | Wr row].
__global__ __launch_bounds__(256) void prep_kernel(
    const float* __restrict__ x, unsigned* __restrict__ xq, long long ND, int ncvt,
    const float* __restrict__ Wl1, const float* __restrict__ Wr1,
    const float* __restrict__ Wl2, const float* __restrict__ Wr2,
    ushort* __restrict__ Wf1, ushort* __restrict__ Wf2,
    const void* __restrict__ ei, int E, int NB, int NBLK, int SH,
    int* __restrict__ histT) {
    __shared__ int h[512];
    const int t = threadIdx.x;
    int bid = blockIdx.x;

    if (bid < ncvt) {
        long long i = ((long long)bid * 256 + t) * 8;
        if (i + 7 < ND) {
            float4 v0 = *reinterpret_cast<const float4*>(x + i);
            float4 v1 = *reinterpret_cast<const float4*>(x + i + 4);
            int p0 = __builtin_amdgcn_cvt_pk_fp8_f32(v0.x, v0.y, 0, false);
            p0 = __builtin_amdgcn_cvt_pk_fp8_f32(v0.z, v0.w, p0, true);
            int p1 = __builtin_amdgcn_cvt_pk_fp8_f32(v1.x, v1.y, 0, false);
            p1 = __builtin_amdgcn_cvt_pk_fp8_f32(v1.z, v1.w, p1, true);
            *reinterpret_cast<uint2*>(reinterpret_cast<unsigned char*>(xq) + i) =
                make_uint2((unsigned)p0, (unsigned)p1);
        } else {
            for (; i < ND; ++i) {
                int pk = __builtin_amdgcn_cvt_pk_fp8_f32(x[i], x[i], 0, false);
                reinterpret_cast<unsigned char*>(xq)[i] = (unsigned char)(pk & 0xff);
            }
        }
        return;
    }
    bid -= ncvt;
    if (bid < 32) {
        int gid = bid * 256 + t;           // 8192 threads: 2 layers x 4096 slots
        int id = gid & 4095;
        const float* Wl = Wl1; const float* Wr = Wr1; ushort* Wf = Wf1;
        if (gid >= 4096) { Wl = Wl2; Wr = Wr2; Wf = Wf2; }
        int lane = id & 63, s = (id >> 6) & 7, j = id >> 9;
        int c = j * 16 + (lane & 15);
        int k = s * 32 + ((lane >> 4) << 3);  // 8 consecutive k from here
        const float* src = (k < 128) ? (Wl + c * 128 + k) : (Wr + c * 128 + (k - 128));
        float4 v0 = *reinterpret_cast<const float4*>(src);
        float4 v1 = *reinterpret_cast<const float4*>(src + 4);
        __hip_bfloat16 o[8];
        o[0] = __float2bfloat16(v0.x); o[1] = __float2bfloat16(v0.y);
        o[2] = __float2bfloat16(v0.z); o[3] = __float2bfloat16(v0.w);
        o[4] = __float2bfloat16(v1.x); o[5] = __float2bfloat16(v1.y);
        o[6] = __float2bfloat16(v1.z); o[7] = __float2bfloat16(v1.w);
        *reinterpret_cast<uint4*>(Wf + (size_t)id * 8) = *reinterpret_cast<uint4*>(o);
        return;
    }
    bid -= 32;
    // partition histogram over buckets for edge tile bid
    for (int b = t; b < 512; b += 256) h[b] = 0;
    bool is64 = ei_is64((const int*)ei);
    __syncthreads();
    const int base = bid * TE;
    for (int i = t; i < TE; i += 256) {
        int e = base + i;
        if (e < E) {
            int d = get_idx(ei, is64, (long long)E + e);
            atomicAdd(&h[d >> SH], 1);
        }
    }
    __syncthreads();
    for (int b = t; b < NB; b += 256) histT[b * NBLK + bid] = h[b];
}

// ---------- 2-kernel exclusive scan (scan_add folded into consumers) ----------
__global__ __launch_bounds__(256) void scan_partial_kernel(int* __restrict__ arr, int Ntot,
                                                           int* __restrict__ bsum) {
    __shared__ int s[SCAN_CHUNK];
    int base = blockIdx.x * SCAN_CHUNK;
    for (int j = threadIdx.x; j < SCAN_CHUNK; j += 256) {
        int i = base + j;
        s[j] = (i < Ntot) ? arr[i] : 0;
    }
    __syncthreads();
    if (threadIdx.x == 0) {
        int run = 0;
        for (int j = 0; j < SCAN_CHUNK; ++j) { int t = s[j]; s[j] = run; run += t; }
        bsum[blockIdx.x] = run;
    }
    __syncthreads();
    for (int j = threadIdx.x; j < SCAN_CHUNK; j += 256) {
        int i = base + j;
        if (i < Ntot) arr[i] = s[j];
    }
}

__global__ __launch_bounds__(256) void scan_top_kernel(int* __restrict__ bsum, int nb) {
    __shared__ int s[1024];
    const int t = threadIdx.x;
    for (int j = t; j < nb; j += 256) s[j] = bsum[j];
    __syncthreads();
    if (t == 0) {
        int run = 0;
        for (int j = 0; j < nb; ++j) { int v = s[j]; s[j] = run; run += v; }
    }
    __syncthreads();
    for (int j = t; j < nb; j += 256) bsum[j] = s[j];
}

// ---------- partition pass 2: scatter edges grouped by bucket ----------
// ebuf entry packed: src (24 bits) | local_dst (8 bits) << 24.
__global__ __launch_bounds__(256) void part_scatter_kernel(const void* __restrict__ ei, int E,
                                                           int NB, int NBLK, int SH,
                                                           const int* __restrict__ histT,
                                                           const int* __restrict__ bsum,
                                                           unsigned* __restrict__ ebuf) {
    __shared__ int cur[512];
    const int t = threadIdx.x;
    bool is64 = ei_is64((const int*)ei);
    for (int b = t; b < NB; b += 256) {
        int idx = b * NBLK + blockIdx.x;
        cur[b] = histT[idx] + bsum[idx >> 10];
    }
    __syncthreads();
    const int base = blockIdx.x * TE;
    for (int i = t; i < TE; i += 256) {
        int e = base + i;
        if (e < E) {
            int s = get_idx(ei, is64, e);
            int d = get_idx(ei, is64, (long long)E + e);
            int pos = atomicAdd(&cur[d >> SH], 1);
            ebuf[pos] = (unsigned)s | ((unsigned)(d & ((1 << SH) - 1)) << 24);
        }
    }
}

// ---------- per-bucket CSR: LDS node-histogram + scan, contiguous col writes ----------
__global__ __launch_bounds__(256) void bucket_csr_kernel(const unsigned* __restrict__ ebuf,
                                                         const int* __restrict__ histT,
                                                         const int* __restrict__ bsum,
                                                         int NB, int NBLK, int SH, int E,
                                                         int N, int* __restrict__ rs,
                                                         int* __restrict__ col) {
    const int b = blockIdx.x, t = threadIdx.x;
    const int nodes = 1 << SH;  // 256
    __shared__ int h[256];
    __shared__ int cur[256];
    __shared__ int sse[2];
    if (t == 0) {
        int i0 = b * NBLK;
        sse[0] = histT[i0] + bsum[i0 >> 10];
        if (b + 1 < NB) {
            int i1 = (b + 1) * NBLK;
            sse[1] = histT[i1] + bsum[i1 >> 10];
        } else {
            sse[1] = E;
        }
    }
    for (int l = t; l < nodes; l += 256) h[l] = 0;
    __syncthreads();
    const int bstart = sse[0], bend = sse[1];
    for (int i = bstart + t; i < bend; i += 256) {
        atomicAdd(&h[ebuf[i] >> 24], 1);
    }
    __syncthreads();
    for (int off = 1; off < nodes; off <<= 1) {
        int v = 0;
        if (t < nodes && t >= off) v = h[t - off];
        __syncthreads();
        if (t < nodes && t >= off) h[t] += v;
        __syncthreads();
    }
    const int node0 = b << SH;
    if (t < nodes) {
        int node = node0 + t;
        if (node < N) rs[node] = bstart + h[t];      // end offset
        cur[t] = bstart + (t ? h[t - 1] : 0);        // start offset
    }
    __syncthreads();
    for (int i = bstart + t; i < bend; i += 256) {
        unsigned ed = ebuf[i];
        int pos = atomicAdd(&cur[ed >> 24], 1);
        col[pos] = (int)(ed & 0xFFFFFFu);
    }
}

// ---------- gather-aggregate (mean), fp8 in / bf16 out ----------
// One QUARTER-WAVE (16 lanes x 8B = full 128B row) owns one node: edges
// accumulate sequentially in-register (4x unrolled, 4 gathers in flight),
// NO cross-lane reduce, full-width coalesced store. 16 nodes per block.
__global__ __launch_bounds__(256) void aggregate_mean_fp8_kernel(
    const unsigned char* __restrict__ xq, const int* __restrict__ rs,
    const int* __restrict__ col, ushort* __restrict__ outm, int N) {
    const int t = threadIdx.x;
    const int v = blockIdx.x * 16 + (t >> 4);
    if (v >= N) return;
    const int lc = t & 15;
    const int start = v ? rs[v - 1] : 0, end = rs[v];
    const unsigned char* xbase = xq + lc * 8;
    f32x2 a0 = {0.f, 0.f}, a1 = {0.f, 0.f}, a2 = {0.f, 0.f}, a3 = {0.f, 0.f};
    int e = start;
    for (; e + 3 < end; e += 4) {
        int s0 = col[e], s1 = col[e + 1], s2 = col[e + 2], s3 = col[e + 3];
        uint2 d0 = *reinterpret_cast<const uint2*>(xbase + (size_t)s0 * D);
        uint2 d1 = *reinterpret_cast<const uint2*>(xbase + (size_t)s1 * D);
        uint2 d2 = *reinterpret_cast<const uint2*>(xbase + (size_t)s2 * D);
        uint2 d3 = *reinterpret_cast<const uint2*>(xbase + (size_t)s3 * D);
        a0 += __builtin_amdgcn_cvt_pk_f32_fp8((int)d0.x, false);
        a1 += __builtin_amdgcn_cvt_pk_f32_fp8((int)d0.x, true);
        a2 += __builtin_amdgcn_cvt_pk_f32_fp8((int)d0.y, false);
        a3 += __builtin_amdgcn_cvt_pk_f32_fp8((int)d0.y, true);
        a0 += __builtin_amdgcn_cvt_pk_f32_fp8((int)d1.x, false);
        a1 += __builtin_amdgcn_cvt_pk_f32_fp8((int)d1.x, true);
        a2 += __builtin_amdgcn_cvt_pk_f32_fp8((int)d1.y, false);
        a3 += __builtin_amdgcn_cvt_pk_f32_fp8((int)d1.y, true);
        a0 += __builtin_amdgcn_cvt_pk_f32_fp8((int)d2.x, false);
        a1 += __builtin_amdgcn_cvt_pk_f32_fp8((int)d2.x, true);
        a2 += __builtin_amdgcn_cvt_pk_f32_fp8((int)d2.y, false);
        a3 += __builtin_amdgcn_cvt_pk_f32_fp8((int)d2.y, true);
        a0 += __builtin_amdgcn_cvt_pk_f32_fp8((int)d3.x, false);
        a1 += __builtin_amdgcn_cvt_pk_f32_fp8((int)d3.x, true);
        a2 += __builtin_amdgcn_cvt_pk_f32_fp8((int)d3.y, false);
        a3 += __builtin_amdgcn_cvt_pk_f32_fp8((int)d3.y, true);
    }
    for (; e < end; ++e) {
        int s0 = col[e];
        uint2 d0 = *reinterpret_cast<const uint2*>(xbase + (size_t)s0 * D);
        a0 += __builtin_amdgcn_cvt_pk_f32_fp8((int)d0.x, false);
        a1 += __builtin_amdgcn_cvt_pk_f32_fp8((int)d0.x, true);
        a2 += __builtin_amdgcn_cvt_pk_f32_fp8((int)d0.y, false);
        a3 += __builtin_amdgcn_cvt_pk_f32_fp8((int)d0.y, true);
    }
    float inv = (end > start) ? 1.0f / (float)(end - start) : 0.f;
    __hip_bfloat16 o[8];
    o[0] = __float2bfloat16(a0.x * inv); o[1] = __float2bfloat16(a0.y * inv);
    o[2] = __float2bfloat16(a1.x * inv); o[3] = __float2bfloat16(a1.y * inv);
    o[4] = __float2bfloat16(a2.x * inv); o[5] = __float2bfloat16(a2.y * inv);
    o[6] = __float2bfloat16(a3.x * inv); o[7] = __float2bfloat16(a3.y * inv);
    *reinterpret_cast<uint4*>(outm + (size_t)v * D + lc * 8) =
        *reinterpret_cast<uint4*>(o);
}

// ---------- MFMA GEMM, LDS-staged frag-major B ----------
// Block = 512 threads = 8 waves, each wave 1 m-tile (16 rows) -> 128 rows/block.
// B (64 KB, frag-major) staged linearly in LDS; inner reads are ds_read_b128
// at lane*16 + immediate -> conflict-free. A frags 16B global loads; self path
// optionally reads f32 directly (layer 1, exact) and converts in-register.
template <typename OutT, bool DUAL, bool SELFF32>
__global__ __launch_bounds__(512) void sage_mfma_kernel(
    const ushort* __restrict__ Ab, const void* __restrict__ Sb,
    const ushort* __restrict__ Wf, const float* __restrict__ bias,
    OutT* __restrict__ out, unsigned char* __restrict__ fq, int N) {
    __shared__ uint4 ldsB[4096];  // 64 KB
    const int t = threadIdx.x;
    {
        const uint4* g = reinterpret_cast<const uint4*>(Wf);
#pragma unroll
        for (int i = 0; i < 8; ++i) ldsB[t + i * 512] = g[t + i * 512];
    }
    __syncthreads();

    const int lane = t & 63, w = t >> 6;
    const int lm = lane & 15;
    const int ksub = (lane >> 4) * 8;
    const int mbase = blockIdx.x * 128 + w * 16;

    int r0 = mbase + lm;
    if (r0 >= N) r0 = N - 1;

    f32x4 acc[8];
#pragma unroll
    for (int j = 0; j < 8; ++j) {
        float bv = bias[j * 16 + lm];
        acc[j] = {bv, bv, bv, bv};
    }

    const ushort* A0 = Ab + (size_t)r0 * D + ksub;
    const ushort* lB = reinterpret_cast<const ushort*>(ldsB) + lane * 8;

#pragma unroll
    for (int s = 0; s < 8; ++s) {
        bf16x8 a;
        if (s < 4) {
            a = *reinterpret_cast<const bf16x8*>(A0 + s * 32);
        } else if constexpr (SELFF32) {
            const float* S0 = (const float*)Sb + (size_t)r0 * D + (s - 4) * 32 + ksub;
            float4 v0 = *reinterpret_cast<const float4*>(S0);
            float4 v1 = *reinterpret_cast<const float4*>(S0 + 4);
            __hip_bfloat16 o[8];
            o[0] = __float2bfloat16(v0.x); o[1] = __float2bfloat16(v0.y);
            o[2] = __float2bfloat16(v0.z); o[3] = __float2bfloat16(v0.w);
            o[4] = __float2bfloat16(v1.x); o[5] = __float2bfloat16(v1.y);
            o[6] = __float2bfloat16(v1.z); o[7] = __float2bfloat16(v1.w);
            a = *reinterpret_cast<bf16x8*>(o);
        } else {
            const ushort* S0 = (const ushort*)Sb + (size_t)r0 * D + ksub;
            a = *reinterpret_cast<const bf16x8*>(S0 + (s - 4) * 32);
        }
#pragma unroll
        for (int j = 0; j < 8; ++j) {
            bf16x8 b = *reinterpret_cast<const bf16x8*>(lB + (j * 8 + s) * 512);
            acc[j] = __builtin_amdgcn_mfma_f32_16x16x32_bf16(a, b, acc[j], 0, 0, 0);
        }
    }

    const int rr = (lane >> 4) * 4;
#pragma unroll
    for (int r = 0; r < 4; ++r) {
        int row = mbase + rr + r;
        if (row < N) {
#pragma unroll
            for (int j = 0; j < 8; ++j) {
                float val = acc[j][r];
                if constexpr (sizeof(OutT) == 2)
                    out[(size_t)row * D + j * 16 + lm] = __float2bfloat16(val);
                else
                    out[(size_t)row * D + j * 16 + lm] = val;
                if constexpr (DUAL) {
                    int pk = __builtin_amdgcn_cvt_pk_fp8_f32(val, val, 0, false);
                    fq[(size_t)row * D + j * 16 + lm] = (unsigned char)(pk & 0xff);
                }
            }
        }
    }
}

extern "C" void kernel_launch(void* const* d_in, const int* in_sizes, int n_in,
                              void* d_out, int out_size, void* d_ws, size_t ws_size,
                              hipStream_t stream) {
    const float* x   = (const float*)d_in[0];
    const void*  ei  = d_in[1];
    const float* Wl1 = (const float*)d_in[2];
    const float* Wr1 = (const float*)d_in[3];
    const float* b1  = (const float*)d_in[4];
    const float* Wl2 = (const float*)d_in[5];
    const float* Wr2 = (const float*)d_in[6];
    const float* b2  = (const float*)d_in[7];
    float* out = (float*)d_out;

    const int N = in_sizes[0] / D;
    const int E = in_sizes[1] / 2;
    const long long ND = (long long)N * D;

    // bucket shift: keep NB <= 512 (N=100000 -> SH=8, NB=391)
    int SH = 8;
    while (((N + (1 << SH) - 1) >> SH) > 512) ++SH;
    const int NB = (N + (1 << SH) - 1) >> SH;
    const int NBLK = (E + TE - 1) / TE;
    const int Ntot = NB * NBLK;
    const int nb2 = (Ntot + SCAN_CHUNK - 1) / SCAN_CHUNK;  // must be <= 1024

    // ws layout (bf16 = ushort)
    ushort* meanb = (ushort*)d_ws;                      // N*D
    ushort* h1b   = meanb + ND;                         // N*D
    ushort* Wf1   = h1b + ND;                           // 4096*8
    ushort* Wf2   = Wf1 + 32768;                        // 4096*8
    int*    rs    = (int*)(Wf2 + 32768);                // N
    int*    col   = rs + N;                             // E
    // transient aliases (dead before their hosts are written):
    int*      histT = (int*)meanb;                      // NB*NBLK (meanb written later)
    int*      bsum  = histT + Ntot;                     // nb2
    unsigned* ebuf  = (unsigned*)h1b;                   // E packed (h1b written later)
    // d_out carve-up (both dead before GEMM2 writes out):
    //   [0, ND): xq fp8; [ND, 2*ND): h1q fp8
    unsigned char* xq  = (unsigned char*)d_out;
    unsigned char* h1q = (unsigned char*)d_out + ND;

    const int ncvt = (int)((ND / 8 + 255) / 256);

    // ---- prep: fp8 convert + frag-major weights + partition histogram ----
    prep_kernel<<<ncvt + 32 + NBLK, 256, 0, stream>>>(
        x, (unsigned*)xq, ND, ncvt, Wl1, Wr1, Wl2, Wr2,
        Wf1, Wf2, ei, E, NB, NBLK, SH, histT);

    // ---- CSR via two-level counting sort (LDS atomics only) ----
    scan_partial_kernel<<<nb2, 256, 0, stream>>>(histT, Ntot, bsum);
    scan_top_kernel<<<1, 256, 0, stream>>>(bsum, nb2);
    part_scatter_kernel<<<NBLK, 256, 0, stream>>>(ei, E, NB, NBLK, SH, histT, bsum, ebuf);
    bucket_csr_kernel<<<NB, 256, 0, stream>>>(ebuf, histT, bsum, NB, NBLK, SH, E, N, rs, col);

    const int agg_grid = (N + 15) / 16;
    const int gemm_grid = (N + 127) / 128;

    // ---- layer 1: gather fp8 x -> mean; GEMM (self f32 exact) -> h1b + h1q ----
    aggregate_mean_fp8_kernel<<<agg_grid, 256, 0, stream>>>(xq, rs, col, meanb, N);
    sage_mfma_kernel<__hip_bfloat16, true, true><<<gemm_grid, 512, 0, stream>>>(
        meanb, x, Wf1, b1, (__hip_bfloat16*)h1b, h1q, N);

    // ---- layer 2: gather fp8 h1 -> mean; GEMM (self bf16) -> out f32 ----
    aggregate_mean_fp8_kernel<<<agg_grid, 256, 0, stream>>>(h1q, rs, col, meanb, N);
    sage_mfma_kernel<float, false, false><<<gemm_grid, 512, 0, stream>>>(
        meanb, h1b, Wf2, b2, out, nullptr, N);
}

// Round 10
// 169.993 us; speedup vs baseline: 2.1548x; 1.0600x over previous
//
#include <hip/hip_runtime.h>
#include <hip/hip_bf16.h>

#define D 128
#define SCAN_CHUNK 1024
#define TE 4096  // edges per partition block

typedef __attribute__((ext_vector_type(8))) short bf16x8;
typedef __attribute__((ext_vector_type(4))) float f32x4;
typedef __attribute__((ext_vector_type(2))) float f32x2;

// ---------- edge-index dtype detection (int64 vs int32, on-device) ----------
__device__ __forceinline__ bool ei_is64(const int* ei32) {
    return (ei32[1] | ei32[3] | ei32[5] | ei32[7]) == 0;
}
__device__ __forceinline__ int get_idx(const void* ei, bool is64, long long pos) {
    return is64 ? (int)((const long long*)ei)[pos] : ((const int*)ei)[pos];
}

// ---------- prep: x->fp8 | frag-major weight build | partition histogram ----------
__global__ __launch_bounds__(256) void prep_kernel(
    const float* __restrict__ x, unsigned* __restrict__ xq, long long ND, int ncvt,
    const float* __restrict__ Wl1, const float* __restrict__ Wr1,
    const float* __restrict__ Wl2, const float* __restrict__ Wr2,
    ushort* __restrict__ Wf1, ushort* __restrict__ Wf2,
    const void* __restrict__ ei, int E, int NB, int NBLK, int SH,
    int* __restrict__ histT) {
    __shared__ int h[512];
    const int t = threadIdx.x;
    int bid = blockIdx.x;

    if (bid < ncvt) {
        long long i = ((long long)bid * 256 + t) * 8;
        if (i + 7 < ND) {
            float4 v0 = *reinterpret_cast<const float4*>(x + i);
            float4 v1 = *reinterpret_cast<const float4*>(x + i + 4);
            int p0 = __builtin_amdgcn_cvt_pk_fp8_f32(v0.x, v0.y, 0, false);
            p0 = __builtin_amdgcn_cvt_pk_fp8_f32(v0.z, v0.w, p0, true);
            int p1 = __builtin_amdgcn_cvt_pk_fp8_f32(v1.x, v1.y, 0, false);
            p1 = __builtin_amdgcn_cvt_pk_fp8_f32(v1.z, v1.w, p1, true);
            *reinterpret_cast<uint2*>(reinterpret_cast<unsigned char*>(xq) + i) =
                make_uint2((unsigned)p0, (unsigned)p1);
        } else {
            for (; i < ND; ++i) {
                int pk = __builtin_amdgcn_cvt_pk_fp8_f32(x[i], x[i], 0, false);
                reinterpret_cast<unsigned char*>(xq)[i] = (unsigned char)(pk & 0xff);
            }
        }
        return;
    }
    bid -= ncvt;
    if (bid < 32) {
        int gid = bid * 256 + t;           // 8192 threads: 2 layers x 4096 slots
        int id = gid & 4095;
        const float* Wl = Wl1; const float* Wr = Wr1; ushort* Wf = Wf1;
        if (gid >= 4096) { Wl = Wl2; Wr = Wr2; Wf = Wf2; }
        int lane = id & 63, s = (id >> 6) & 7, j = id >> 9;
        int c = j * 16 + (lane & 15);
        int k = s * 32 + ((lane >> 4) << 3);  // 8 consecutive k from here
        const float* src = (k < 128) ? (Wl + c * 128 + k) : (Wr + c * 128 + (k - 128));
        float4 v0 = *reinterpret_cast<const float4*>(src);
        float4 v1 = *reinterpret_cast<const float4*>(src + 4);
        __hip_bfloat16 o[8];
        o[0] = __float2bfloat16(v0.x); o[1] = __float2bfloat16(v0.y);
        o[2] = __float2bfloat16(v0.z); o[3] = __float2bfloat16(v0.w);
        o[4] = __float2bfloat16(v1.x); o[5] = __float2bfloat16(v1.y);
        o[6] = __float2bfloat16(v1.z); o[7] = __float2bfloat16(v1.w);
        *reinterpret_cast<uint4*>(Wf + (size_t)id * 8) = *reinterpret_cast<uint4*>(o);
        return;
    }
    bid -= 32;
    // partition histogram over buckets for edge tile bid
    for (int b = t; b < 512; b += 256) h[b] = 0;
    bool is64 = ei_is64((const int*)ei);
    __syncthreads();
    const int base = bid * TE;
    for (int i = t; i < TE; i += 256) {
        int e = base + i;
        if (e < E) {
            int d = get_idx(ei, is64, (long long)E + e);
            atomicAdd(&h[d >> SH], 1);
        }
    }
    __syncthreads();
    for (int b = t; b < NB; b += 256) histT[b * NBLK + bid] = h[b];
}

// ---------- single-pass chunk scan: arr -> per-chunk exclusive, bsum = chunk sums ----------
__global__ __launch_bounds__(256) void scan_partial_kernel(int* __restrict__ arr, int Ntot,
                                                           int* __restrict__ bsum) {
    __shared__ int ws[256];
    const int t = threadIdx.x;
    const int i0 = blockIdx.x * SCAN_CHUNK + t * 4;
    int4 v = {0, 0, 0, 0};
    if (i0 + 3 < Ntot) {
        v = *reinterpret_cast<const int4*>(arr + i0);
    } else {
        if (i0 < Ntot) v.x = arr[i0];
        if (i0 + 1 < Ntot) v.y = arr[i0 + 1];
        if (i0 + 2 < Ntot) v.z = arr[i0 + 2];
        if (i0 + 3 < Ntot) v.w = arr[i0 + 3];
    }
    ws[t] = v.x + v.y + v.z + v.w;
    __syncthreads();
    for (int off = 1; off < 256; off <<= 1) {
        int val = (t >= off) ? ws[t - off] : 0;
        __syncthreads();
        ws[t] += val;
        __syncthreads();
    }
    int ex = t ? ws[t - 1] : 0;
    int e0 = ex, e1 = ex + v.x, e2 = e1 + v.y, e3 = e2 + v.z;
    if (i0 + 3 < Ntot) {
        *reinterpret_cast<int4*>(arr + i0) = make_int4(e0, e1, e2, e3);
    } else {
        if (i0 < Ntot) arr[i0] = e0;
        if (i0 + 1 < Ntot) arr[i0 + 1] = e1;
        if (i0 + 2 < Ntot) arr[i0 + 2] = e2;
        if (i0 + 3 < Ntot) arr[i0 + 3] = e3;
    }
    if (t == 255) bsum[blockIdx.x] = ws[255];
}

// ---------- in-block inclusive scan of bsum[0..nb2) into sb[256] (nb2 <= 256) ----------
__device__ __forceinline__ void scan_bsum_lds(const int* __restrict__ bsum, int nb2,
                                              int* sb) {
    const int t = threadIdx.x;
    sb[t] = (t < nb2) ? bsum[t] : 0;
    __syncthreads();
    for (int off = 1; off < 256; off <<= 1) {
        int v = (t >= off) ? sb[t - off] : 0;
        __syncthreads();
        sb[t] += v;
        __syncthreads();
    }
    // sb[j] = inclusive sum; exclusive prefix of chunk j = (j ? sb[j-1] : 0)
}

// ---------- partition pass 2: scatter edges grouped by bucket ----------
// ebuf entry packed: src (24 bits) | local_dst (8 bits) << 24.
__global__ __launch_bounds__(256) void part_scatter_kernel(const void* __restrict__ ei, int E,
                                                           int NB, int NBLK, int SH,
                                                           const int* __restrict__ histT,
                                                           const int* __restrict__ bsum,
                                                           int nb2,
                                                           unsigned* __restrict__ ebuf) {
    __shared__ int cur[512];
    __shared__ int sb[256];
    const int t = threadIdx.x;
    bool is64 = ei_is64((const int*)ei);
    scan_bsum_lds(bsum, nb2, sb);
    for (int b = t; b < NB; b += 256) {
        int idx = b * NBLK + blockIdx.x;
        int c = idx >> 10;
        cur[b] = histT[idx] + (c ? sb[c - 1] : 0);
    }
    __syncthreads();
    const int base = blockIdx.x * TE;
    for (int i = t; i < TE; i += 256) {
        int e = base + i;
        if (e < E) {
            int s = get_idx(ei, is64, e);
            int d = get_idx(ei, is64, (long long)E + e);
            int pos = atomicAdd(&cur[d >> SH], 1);
            ebuf[pos] = (unsigned)s | ((unsigned)(d & ((1 << SH) - 1)) << 24);
        }
    }
}

// ---------- per-bucket CSR: LDS node-histogram + scan, contiguous col writes ----------
__global__ __launch_bounds__(256) void bucket_csr_kernel(const unsigned* __restrict__ ebuf,
                                                         const int* __restrict__ histT,
                                                         const int* __restrict__ bsum,
                                                         int nb2,
                                                         int NB, int NBLK, int SH, int E,
                                                         int N, int* __restrict__ rs,
                                                         int* __restrict__ col) {
    const int b = blockIdx.x, t = threadIdx.x;
    const int nodes = 1 << SH;  // 256
    __shared__ int h[256];
    __shared__ int cur[256];
    __shared__ int sb[256];
    __shared__ int sse[2];
    scan_bsum_lds(bsum, nb2, sb);
    if (t == 0) {
        int i0 = b * NBLK;
        int c0 = i0 >> 10;
        sse[0] = histT[i0] + (c0 ? sb[c0 - 1] : 0);
        if (b + 1 < NB) {
            int i1 = (b + 1) * NBLK;
            int c1 = i1 >> 10;
            sse[1] = histT[i1] + (c1 ? sb[c1 - 1] : 0);
        } else {
            sse[1] = E;
        }
    }
    h[t] = 0;
    __syncthreads();
    const int bstart = sse[0], bend = sse[1];
    for (int i = bstart + t; i < bend; i += 256) {
        atomicAdd(&h[ebuf[i] >> 24], 1);
    }
    __syncthreads();
    for (int off = 1; off < nodes; off <<= 1) {
        int v = (t >= off) ? h[t - off] : 0;
        __syncthreads();
        h[t] += v;
        __syncthreads();
    }
    const int node0 = b << SH;
    {
        int node = node0 + t;
        if (node < N) rs[node] = bstart + h[t];      // end offset
        cur[t] = bstart + (t ? h[t - 1] : 0);        // start offset
    }
    __syncthreads();
    for (int i = bstart + t; i < bend; i += 256) {
        unsigned ed = ebuf[i];
        int pos = atomicAdd(&cur[ed >> 24], 1);
        col[pos] = (int)(ed & 0xFFFFFFu);
    }
}

// ---------- gather-aggregate (mean), fp8 in / bf16 out ----------
// One QUARTER-WAVE (16 lanes x 8B = full 128B row) owns one node; edges
// accumulate in-register (4x unrolled), no cross-lane reduce, coalesced store.
// All gather addresses are 32-bit byte offsets from an SGPR base.
__global__ __launch_bounds__(256) void aggregate_mean_fp8_kernel(
    const unsigned char* __restrict__ xq, const int* __restrict__ rs,
    const int* __restrict__ col, ushort* __restrict__ outm, int N) {
    const int t = threadIdx.x;
    const int v = blockIdx.x * 16 + (t >> 4);
    if (v >= N) return;
    const unsigned lcoff = (unsigned)(t & 15) * 8u;
    const int start = v ? rs[v - 1] : 0, end = rs[v];
    f32x2 a0 = {0.f, 0.f}, a1 = {0.f, 0.f}, a2 = {0.f, 0.f}, a3 = {0.f, 0.f};
    int e = start;
    for (; e + 3 < end; e += 4) {
        unsigned o0 = ((unsigned)col[e] << 7) + lcoff;
        unsigned o1 = ((unsigned)col[e + 1] << 7) + lcoff;
        unsigned o2 = ((unsigned)col[e + 2] << 7) + lcoff;
        unsigned o3 = ((unsigned)col[e + 3] << 7) + lcoff;
        uint2 d0 = *reinterpret_cast<const uint2*>(xq + o0);
        uint2 d1 = *reinterpret_cast<const uint2*>(xq + o1);
        uint2 d2 = *reinterpret_cast<const uint2*>(xq + o2);
        uint2 d3 = *reinterpret_cast<const uint2*>(xq + o3);
        a0 += __builtin_amdgcn_cvt_pk_f32_fp8((int)d0.x, false);
        a1 += __builtin_amdgcn_cvt_pk_f32_fp8((int)d0.x, true);
        a2 += __builtin_amdgcn_cvt_pk_f32_fp8((int)d0.y, false);
        a3 += __builtin_amdgcn_cvt_pk_f32_fp8((int)d0.y, true);
        a0 += __builtin_amdgcn_cvt_pk_f32_fp8((int)d1.x, false);
        a1 += __builtin_amdgcn_cvt_pk_f32_fp8((int)d1.x, true);
        a2 += __builtin_amdgcn_cvt_pk_f32_fp8((int)d1.y, false);
        a3 += __builtin_amdgcn_cvt_pk_f32_fp8((int)d1.y, true);
        a0 += __builtin_amdgcn_cvt_pk_f32_fp8((int)d2.x, false);
        a1 += __builtin_amdgcn_cvt_pk_f32_fp8((int)d2.x, true);
        a2 += __builtin_amdgcn_cvt_pk_f32_fp8((int)d2.y, false);
        a3 += __builtin_amdgcn_cvt_pk_f32_fp8((int)d2.y, true);
        a0 += __builtin_amdgcn_cvt_pk_f32_fp8((int)d3.x, false);
        a1 += __builtin_amdgcn_cvt_pk_f32_fp8((int)d3.x, true);
        a2 += __builtin_amdgcn_cvt_pk_f32_fp8((int)d3.y, false);
        a3 += __builtin_amdgcn_cvt_pk_f32_fp8((int)d3.y, true);
    }
    for (; e < end; ++e) {
        unsigned o0 = ((unsigned)col[e] << 7) + lcoff;
        uint2 d0 = *reinterpret_cast<const uint2*>(xq + o0);
        a0 += __builtin_amdgcn_cvt_pk_f32_fp8((int)d0.x, false);
        a1 += __builtin_amdgcn_cvt_pk_f32_fp8((int)d0.x, true);
        a2 += __builtin_amdgcn_cvt_pk_f32_fp8((int)d0.y, false);
        a3 += __builtin_amdgcn_cvt_pk_f32_fp8((int)d0.y, true);
    }
    float inv = (end > start) ? 1.0f / (float)(end - start) : 0.f;
    __hip_bfloat16 o[8];
    o[0] = __float2bfloat16(a0.x * inv); o[1] = __float2bfloat16(a0.y * inv);
    o[2] = __float2bfloat16(a1.x * inv); o[3] = __float2bfloat16(a1.y * inv);
    o[4] = __float2bfloat16(a2.x * inv); o[5] = __float2bfloat16(a2.y * inv);
    o[6] = __float2bfloat16(a3.x * inv); o[7] = __float2bfloat16(a3.y * inv);
    *reinterpret_cast<uint4*>(outm + (size_t)v * D + ((t & 15) << 3)) =
        *reinterpret_cast<uint4*>(o);
}

// ---------- MFMA GEMM, LDS-staged frag-major B ----------
template <typename OutT, bool DUAL, bool SELFF32>
__global__ __launch_bounds__(512) void sage_mfma_kernel(
    const ushort* __restrict__ Ab, const void* __restrict__ Sb,
    const ushort* __restrict__ Wf, const float* __restrict__ bias,
    OutT* __restrict__ out, unsigned char* __restrict__ fq, int N) {
    __shared__ uint4 ldsB[4096];  // 64 KB
    const int t = threadIdx.x;
    {
        const uint4* g = reinterpret_cast<const uint4*>(Wf);
#pragma unroll
        for (int i = 0; i < 8; ++i) ldsB[t + i * 512] = g[t + i * 512];
    }
    __syncthreads();

    const int lane = t & 63, w = t >> 6;
    const int lm = lane & 15;
    const int ksub = (lane >> 4) * 8;
    const int mbase = blockIdx.x * 128 + w * 16;

    int r0 = mbase + lm;
    if (r0 >= N) r0 = N - 1;

    f32x4 acc[8];
#pragma unroll
    for (int j = 0; j < 8; ++j) {
        float bv = bias[j * 16 + lm];
        acc[j] = {bv, bv, bv, bv};
    }

    const ushort* A0 = Ab + (size_t)r0 * D + ksub;
    const ushort* lB = reinterpret_cast<const ushort*>(ldsB) + lane * 8;

#pragma unroll
    for (int s = 0; s < 8; ++s) {
        bf16x8 a;
        if (s < 4) {
            a = *reinterpret_cast<const bf16x8*>(A0 + s * 32);
        } else if constexpr (SELFF32) {
            const float* S0 = (const float*)Sb + (size_t)r0 * D + (s - 4) * 32 + ksub;
            float4 v0 = *reinterpret_cast<const float4*>(S0);
            float4 v1 = *reinterpret_cast<const float4*>(S0 + 4);
            __hip_bfloat16 o[8];
            o[0] = __float2bfloat16(v0.x); o[1] = __float2bfloat16(v0.y);
            o[2] = __float2bfloat16(v0.z); o[3] = __float2bfloat16(v0.w);
            o[4] = __float2bfloat16(v1.x); o[5] = __float2bfloat16(v1.y);
            o[6] = __float2bfloat16(v1.z); o[7] = __float2bfloat16(v1.w);
            a = *reinterpret_cast<bf16x8*>(o);
        } else {
            const ushort* S0 = (const ushort*)Sb + (size_t)r0 * D + ksub;
            a = *reinterpret_cast<const bf16x8*>(S0 + (s - 4) * 32);
        }
#pragma unroll
        for (int j = 0; j < 8; ++j) {
            bf16x8 b = *reinterpret_cast<const bf16x8*>(lB + (j * 8 + s) * 512);
            acc[j] = __builtin_amdgcn_mfma_f32_16x16x32_bf16(a, b, acc[j], 0, 0, 0);
        }
    }

    const int rr = (lane >> 4) * 4;
#pragma unroll
    for (int r = 0; r < 4; ++r) {
        int row = mbase + rr + r;
        if (row < N) {
#pragma unroll
            for (int j = 0; j < 8; ++j) {
                float val = acc[j][r];
                if constexpr (sizeof(OutT) == 2)
                    out[(size_t)row * D + j * 16 + lm] = __float2bfloat16(val);
                else
                    out[(size_t)row * D + j * 16 + lm] = val;
                if constexpr (DUAL) {
                    int pk = __builtin_amdgcn_cvt_pk_fp8_f32(val, val, 0, false);
                    fq[(size_t)row * D + j * 16 + lm] = (unsigned char)(pk & 0xff);
                }
            }
        }
    }
}

extern "C" void kernel_launch(void* const* d_in, const int* in_sizes, int n_in,
                              void* d_out, int out_size, void* d_ws, size_t ws_size,
                              hipStream_t stream) {
    const float* x   = (const float*)d_in[0];
    const void*  ei  = d_in[1];
    const float* Wl1 = (const float*)d_in[2];
    const float* Wr1 = (const float*)d_in[3];
    const float* b1  = (const float*)d_in[4];
    const float* Wl2 = (const float*)d_in[5];
    const float* Wr2 = (const float*)d_in[6];
    const float* b2  = (const float*)d_in[7];
    float* out = (float*)d_out;

    const int N = in_sizes[0] / D;
    const int E = in_sizes[1] / 2;
    const long long ND = (long long)N * D;

    // bucket shift: keep NB <= 512 (N=100000 -> SH=8, NB=391)
    int SH = 8;
    while (((N + (1 << SH) - 1) >> SH) > 512) ++SH;
    const int NB = (N + (1 << SH) - 1) >> SH;
    const int NBLK = (E + TE - 1) / TE;
    const int Ntot = NB * NBLK;
    const int nb2 = (Ntot + SCAN_CHUNK - 1) / SCAN_CHUNK;  // must be <= 256

    // ws layout (bf16 = ushort)
    ushort* meanb = (ushort*)d_ws;                      // N*D
    ushort* h1b   = meanb + ND;                         // N*D
    ushort* Wf1   = h1b + ND;                           // 4096*8
    ushort* Wf2   = Wf1 + 32768;                        // 4096*8
    int*    rs    = (int*)(Wf2 + 32768);                // N
    int*    col   = rs + N;                             // E
    // transient aliases (dead before their hosts are written):
    int*      histT = (int*)meanb;                      // NB*NBLK (meanb written later)
    int*      bsum  = histT + Ntot;                     // nb2
    unsigned* ebuf  = (unsigned*)h1b;                   // E packed (h1b written later)
    // d_out carve-up (both dead before GEMM2 writes out):
    //   [0, ND): xq fp8; [ND, 2*ND): h1q fp8
    unsigned char* xq  = (unsigned char*)d_out;
    unsigned char* h1q = (unsigned char*)d_out + ND;

    const int ncvt = (int)((ND / 8 + 255) / 256);

    // ---- prep: fp8 convert + frag-major weights + partition histogram ----
    prep_kernel<<<ncvt + 32 + NBLK, 256, 0, stream>>>(
        x, (unsigned*)xq, ND, ncvt, Wl1, Wr1, Wl2, Wr2,
        Wf1, Wf2, ei, E, NB, NBLK, SH, histT);

    // ---- CSR via two-level counting sort (LDS atomics only; no scan_top) ----
    scan_partial_kernel<<<nb2, 256, 0, stream>>>(histT, Ntot, bsum);
    part_scatter_kernel<<<NBLK, 256, 0, stream>>>(ei, E, NB, NBLK, SH, histT, bsum, nb2, ebuf);
    bucket_csr_kernel<<<NB, 256, 0, stream>>>(ebuf, histT, bsum, nb2, NB, NBLK, SH, E, N, rs, col);

    const int agg_grid = (N + 15) / 16;
    const int gemm_grid = (N + 127) / 128;

    // ---- layer 1: gather fp8 x -> mean; GEMM (self f32 exact) -> h1b + h1q ----
    aggregate_mean_fp8_kernel<<<agg_grid, 256, 0, stream>>>(xq, rs, col, meanb, N);
    sage_mfma_kernel<__hip_bfloat16, true, true><<<gemm_grid, 512, 0, stream>>>(
        meanb, x, Wf1, b1, (__hip_bfloat16*)h1b, h1q, N);

    // ---- layer 2: gather fp8 h1 -> mean; GEMM (self bf16) -> out f32 ----
    aggregate_mean_fp8_kernel<<<agg_grid, 256, 0, stream>>>(h1q, rs, col, meanb, N);
    sage_mfma_kernel<float, false, false><<<gemm_grid, 512, 0, stream>>>(
        meanb, h1b, Wf2, b2, out, nullptr, N);
}

// Round 11
// 160.958 us; speedup vs baseline: 2.2757x; 1.0561x over previous
//
#include <hip/hip_runtime.h>
#include <hip/hip_bf16.h>

#define D 128
#define SCAN_CHUNK 1024
#define TE 4096  // edges per partition block

typedef __attribute__((ext_vector_type(8))) short bf16x8;
typedef __attribute__((ext_vector_type(4))) float f32x4;
typedef __attribute__((ext_vector_type(2))) float f32x2;

// ---------- edge-index dtype detection (int64 vs int32, on-device) ----------
__device__ __forceinline__ bool ei_is64(const int* ei32) {
    return (ei32[1] | ei32[3] | ei32[5] | ei32[7]) == 0;
}
__device__ __forceinline__ int get_idx(const void* ei, bool is64, long long pos) {
    return is64 ? (int)((const long long*)ei)[pos] : ((const int*)ei)[pos];
}

// ---------- prep: x->fp8 | frag-major weight build | partition histogram ----------
__global__ __launch_bounds__(256) void prep_kernel(
    const float* __restrict__ x, unsigned* __restrict__ xq, long long ND, int ncvt,
    const float* __restrict__ Wl1, const float* __restrict__ Wr1,
    const float* __restrict__ Wl2, const float* __restrict__ Wr2,
    ushort* __restrict__ Wf1, ushort* __restrict__ Wf2,
    const void* __restrict__ ei, int E, int NB, int NBLK, int SH,
    int* __restrict__ histT) {
    __shared__ int h[512];
    const int t = threadIdx.x;
    int bid = blockIdx.x;

    if (bid < ncvt) {
        long long i = ((long long)bid * 256 + t) * 8;
        if (i + 7 < ND) {
            float4 v0 = *reinterpret_cast<const float4*>(x + i);
            float4 v1 = *reinterpret_cast<const float4*>(x + i + 4);
            int p0 = __builtin_amdgcn_cvt_pk_fp8_f32(v0.x, v0.y, 0, false);
            p0 = __builtin_amdgcn_cvt_pk_fp8_f32(v0.z, v0.w, p0, true);
            int p1 = __builtin_amdgcn_cvt_pk_fp8_f32(v1.x, v1.y, 0, false);
            p1 = __builtin_amdgcn_cvt_pk_fp8_f32(v1.z, v1.w, p1, true);
            *reinterpret_cast<uint2*>(reinterpret_cast<unsigned char*>(xq) + i) =
                make_uint2((unsigned)p0, (unsigned)p1);
        } else {
            for (; i < ND; ++i) {
                int pk = __builtin_amdgcn_cvt_pk_fp8_f32(x[i], x[i], 0, false);
                reinterpret_cast<unsigned char*>(xq)[i] = (unsigned char)(pk & 0xff);
            }
        }
        return;
    }
    bid -= ncvt;
    if (bid < 32) {
        int gid = bid * 256 + t;           // 8192 threads: 2 layers x 4096 slots
        int id = gid & 4095;
        const float* Wl = Wl1; const float* Wr = Wr1; ushort* Wf = Wf1;
        if (gid >= 4096) { Wl = Wl2; Wr = Wr2; Wf = Wf2; }
        int lane = id & 63, s = (id >> 6) & 7, j = id >> 9;
        int c = j * 16 + (lane & 15);
        int k = s * 32 + ((lane >> 4) << 3);  // 8 consecutive k from here
        const float* src = (k < 128) ? (Wl + c * 128 + k) : (Wr + c * 128 + (k - 128));
        float4 v0 = *reinterpret_cast<const float4*>(src);
        float4 v1 = *reinterpret_cast<const float4*>(src + 4);
        __hip_bfloat16 o[8];
        o[0] = __float2bfloat16(v0.x); o[1] = __float2bfloat16(v0.y);
        o[2] = __float2bfloat16(v0.z); o[3] = __float2bfloat16(v0.w);
        o[4] = __float2bfloat16(v1.x); o[5] = __float2bfloat16(v1.y);
        o[6] = __float2bfloat16(v1.z); o[7] = __float2bfloat16(v1.w);
        *reinterpret_cast<uint4*>(Wf + (size_t)id * 8) = *reinterpret_cast<uint4*>(o);
        return;
    }
    bid -= 32;
    // partition histogram over buckets for edge tile bid
    for (int b = t; b < 512; b += 256) h[b] = 0;
    bool is64 = ei_is64((const int*)ei);
    __syncthreads();
    const int base = bid * TE;
    for (int i = t; i < TE; i += 256) {
        int e = base + i;
        if (e < E) {
            int d = get_idx(ei, is64, (long long)E + e);
            atomicAdd(&h[d >> SH], 1);
        }
    }
    __syncthreads();
    for (int b = t; b < NB; b += 256) histT[b * NBLK + bid] = h[b];
}

// ---------- single-pass chunk scan: arr -> per-chunk exclusive, bsum = chunk sums ----------
__global__ __launch_bounds__(256) void scan_partial_kernel(int* __restrict__ arr, int Ntot,
                                                           int* __restrict__ bsum) {
    __shared__ int ws[256];
    const int t = threadIdx.x;
    const int i0 = blockIdx.x * SCAN_CHUNK + t * 4;
    int4 v = {0, 0, 0, 0};
    if (i0 + 3 < Ntot) {
        v = *reinterpret_cast<const int4*>(arr + i0);
    } else {
        if (i0 < Ntot) v.x = arr[i0];
        if (i0 + 1 < Ntot) v.y = arr[i0 + 1];
        if (i0 + 2 < Ntot) v.z = arr[i0 + 2];
        if (i0 + 3 < Ntot) v.w = arr[i0 + 3];
    }
    ws[t] = v.x + v.y + v.z + v.w;
    __syncthreads();
    for (int off = 1; off < 256; off <<= 1) {
        int val = (t >= off) ? ws[t - off] : 0;
        __syncthreads();
        ws[t] += val;
        __syncthreads();
    }
    int ex = t ? ws[t - 1] : 0;
    int e0 = ex, e1 = ex + v.x, e2 = e1 + v.y, e3 = e2 + v.z;
    if (i0 + 3 < Ntot) {
        *reinterpret_cast<int4*>(arr + i0) = make_int4(e0, e1, e2, e3);
    } else {
        if (i0 < Ntot) arr[i0] = e0;
        if (i0 + 1 < Ntot) arr[i0 + 1] = e1;
        if (i0 + 2 < Ntot) arr[i0 + 2] = e2;
        if (i0 + 3 < Ntot) arr[i0 + 3] = e3;
    }
    if (t == 255) bsum[blockIdx.x] = ws[255];
}

// ---------- in-block inclusive scan of bsum[0..nb2) into sb[256] (nb2 <= 256) ----------
__device__ __forceinline__ void scan_bsum_lds(const int* __restrict__ bsum, int nb2,
                                              int* sb) {
    const int t = threadIdx.x;
    sb[t] = (t < nb2) ? bsum[t] : 0;
    __syncthreads();
    for (int off = 1; off < 256; off <<= 1) {
        int v = (t >= off) ? sb[t - off] : 0;
        __syncthreads();
        sb[t] += v;
        __syncthreads();
    }
    // sb[j] = inclusive sum; exclusive prefix of chunk j = (j ? sb[j-1] : 0)
}

// ---------- partition pass 2: scatter edges grouped by bucket ----------
// ebuf entry packed: src (24 bits) | local_dst (8 bits) << 24.
__global__ __launch_bounds__(256) void part_scatter_kernel(const void* __restrict__ ei, int E,
                                                           int NB, int NBLK, int SH,
                                                           const int* __restrict__ histT,
                                                           const int* __restrict__ bsum,
                                                           int nb2,
                                                           unsigned* __restrict__ ebuf) {
    __shared__ int cur[512];
    __shared__ int sb[256];
    const int t = threadIdx.x;
    bool is64 = ei_is64((const int*)ei);
    scan_bsum_lds(bsum, nb2, sb);
    for (int b = t; b < NB; b += 256) {
        int idx = b * NBLK + blockIdx.x;
        int c = idx >> 10;
        cur[b] = histT[idx] + (c ? sb[c - 1] : 0);
    }
    __syncthreads();
    const int base = blockIdx.x * TE;
    for (int i = t; i < TE; i += 256) {
        int e = base + i;
        if (e < E) {
            int s = get_idx(ei, is64, e);
            int d = get_idx(ei, is64, (long long)E + e);
            int pos = atomicAdd(&cur[d >> SH], 1);
            ebuf[pos] = (unsigned)s | ((unsigned)(d & ((1 << SH) - 1)) << 24);
        }
    }
}

// ---------- per-bucket CSR: LDS node-histogram + scan, contiguous col writes ----------
__global__ __launch_bounds__(256) void bucket_csr_kernel(const unsigned* __restrict__ ebuf,
                                                         const int* __restrict__ histT,
                                                         const int* __restrict__ bsum,
                                                         int nb2,
                                                         int NB, int NBLK, int SH, int E,
                                                         int N, int* __restrict__ rs,
                                                         int* __restrict__ col) {
    const int b = blockIdx.x, t = threadIdx.x;
    const int nodes = 1 << SH;  // 256
    __shared__ int h[256];
    __shared__ int cur[256];
    __shared__ int sb[256];
    __shared__ int sse[2];
    scan_bsum_lds(bsum, nb2, sb);
    if (t == 0) {
        int i0 = b * NBLK;
        int c0 = i0 >> 10;
        sse[0] = histT[i0] + (c0 ? sb[c0 - 1] : 0);
        if (b + 1 < NB) {
            int i1 = (b + 1) * NBLK;
            int c1 = i1 >> 10;
            sse[1] = histT[i1] + (c1 ? sb[c1 - 1] : 0);
        } else {
            sse[1] = E;
        }
    }
    h[t] = 0;
    __syncthreads();
    const int bstart = sse[0], bend = sse[1];
    for (int i = bstart + t; i < bend; i += 256) {
        atomicAdd(&h[ebuf[i] >> 24], 1);
    }
    __syncthreads();
    for (int off = 1; off < nodes; off <<= 1) {
        int v = (t >= off) ? h[t - off] : 0;
        __syncthreads();
        h[t] += v;
        __syncthreads();
    }
    const int node0 = b << SH;
    {
        int node = node0 + t;
        if (node < N) rs[node] = bstart + h[t];      // end offset
        cur[t] = bstart + (t ? h[t - 1] : 0);        // start offset
    }
    __syncthreads();
    for (int i = bstart + t; i < bend; i += 256) {
        unsigned ed = ebuf[i];
        int pos = atomicAdd(&cur[ed >> 24], 1);
        col[pos] = (int)(ed & 0xFFFFFFu);
    }
}

// ---------- gather-aggregate (mean), fp8 in / bf16 out ----------
// One QUARTER-WAVE (16 lanes x 8B = full 128B row) owns one node.
// 8-wide main batch (8 col + 8 gathers in flight) -> 4-wide -> one MASKED
// final batch (clamped index, raw bytes zeroed via cndmask; fp8 0x00 -> 0.0).
__device__ __forceinline__ void acc8(f32x2& a0, f32x2& a1, f32x2& a2, f32x2& a3,
                                     uint2 d) {
    a0 += __builtin_amdgcn_cvt_pk_f32_fp8((int)d.x, false);
    a1 += __builtin_amdgcn_cvt_pk_f32_fp8((int)d.x, true);
    a2 += __builtin_amdgcn_cvt_pk_f32_fp8((int)d.y, false);
    a3 += __builtin_amdgcn_cvt_pk_f32_fp8((int)d.y, true);
}

__global__ __launch_bounds__(256) void aggregate_mean_fp8_kernel(
    const unsigned char* __restrict__ xq, const int* __restrict__ rs,
    const int* __restrict__ col, ushort* __restrict__ outm, int N) {
    const int t = threadIdx.x;
    const int v = blockIdx.x * 16 + (t >> 4);
    if (v >= N) return;
    const unsigned lcoff = (unsigned)(t & 15) * 8u;
    const int start = v ? rs[v - 1] : 0, end = rs[v];
    f32x2 a0 = {0.f, 0.f}, a1 = {0.f, 0.f}, a2 = {0.f, 0.f}, a3 = {0.f, 0.f};
    int e = start;
    // ---- 8-wide main batches ----
    for (; e + 7 < end; e += 8) {
        int c0 = col[e], c1 = col[e + 1], c2 = col[e + 2], c3 = col[e + 3];
        int c4 = col[e + 4], c5 = col[e + 5], c6 = col[e + 6], c7 = col[e + 7];
        uint2 d0 = *reinterpret_cast<const uint2*>(xq + (((unsigned)c0) << 7) + lcoff);
        uint2 d1 = *reinterpret_cast<const uint2*>(xq + (((unsigned)c1) << 7) + lcoff);
        uint2 d2 = *reinterpret_cast<const uint2*>(xq + (((unsigned)c2) << 7) + lcoff);
        uint2 d3 = *reinterpret_cast<const uint2*>(xq + (((unsigned)c3) << 7) + lcoff);
        uint2 d4 = *reinterpret_cast<const uint2*>(xq + (((unsigned)c4) << 7) + lcoff);
        uint2 d5 = *reinterpret_cast<const uint2*>(xq + (((unsigned)c5) << 7) + lcoff);
        uint2 d6 = *reinterpret_cast<const uint2*>(xq + (((unsigned)c6) << 7) + lcoff);
        uint2 d7 = *reinterpret_cast<const uint2*>(xq + (((unsigned)c7) << 7) + lcoff);
        acc8(a0, a1, a2, a3, d0); acc8(a0, a1, a2, a3, d1);
        acc8(a0, a1, a2, a3, d2); acc8(a0, a1, a2, a3, d3);
        acc8(a0, a1, a2, a3, d4); acc8(a0, a1, a2, a3, d5);
        acc8(a0, a1, a2, a3, d6); acc8(a0, a1, a2, a3, d7);
    }
    // ---- 4-wide ----
    for (; e + 3 < end; e += 4) {
        int c0 = col[e], c1 = col[e + 1], c2 = col[e + 2], c3 = col[e + 3];
        uint2 d0 = *reinterpret_cast<const uint2*>(xq + (((unsigned)c0) << 7) + lcoff);
        uint2 d1 = *reinterpret_cast<const uint2*>(xq + (((unsigned)c1) << 7) + lcoff);
        uint2 d2 = *reinterpret_cast<const uint2*>(xq + (((unsigned)c2) << 7) + lcoff);
        uint2 d3 = *reinterpret_cast<const uint2*>(xq + (((unsigned)c3) << 7) + lcoff);
        acc8(a0, a1, a2, a3, d0); acc8(a0, a1, a2, a3, d1);
        acc8(a0, a1, a2, a3, d2); acc8(a0, a1, a2, a3, d3);
    }
    // ---- masked final batch (0..3 edges, fully pipelined) ----
    if (e < end) {
        const int l = end - 1;
        int i1 = e + 1 < end ? e + 1 : l;
        int i2 = e + 2 < end ? e + 2 : l;
        int c0 = col[e], c1 = col[i1], c2 = col[i2];
        uint2 d0 = *reinterpret_cast<const uint2*>(xq + (((unsigned)c0) << 7) + lcoff);
        uint2 d1 = *reinterpret_cast<const uint2*>(xq + (((unsigned)c1) << 7) + lcoff);
        uint2 d2 = *reinterpret_cast<const uint2*>(xq + (((unsigned)c2) << 7) + lcoff);
        d1.x = (e + 1 < end) ? d1.x : 0u; d1.y = (e + 1 < end) ? d1.y : 0u;
        d2.x = (e + 2 < end) ? d2.x : 0u; d2.y = (e + 2 < end) ? d2.y : 0u;
        acc8(a0, a1, a2, a3, d0); acc8(a0, a1, a2, a3, d1);
        acc8(a0, a1, a2, a3, d2);
    }
    float inv = (end > start) ? 1.0f / (float)(end - start) : 0.f;
    __hip_bfloat16 o[8];
    o[0] = __float2bfloat16(a0.x * inv); o[1] = __float2bfloat16(a0.y * inv);
    o[2] = __float2bfloat16(a1.x * inv); o[3] = __float2bfloat16(a1.y * inv);
    o[4] = __float2bfloat16(a2.x * inv); o[5] = __float2bfloat16(a2.y * inv);
    o[6] = __float2bfloat16(a3.x * inv); o[7] = __float2bfloat16(a3.y * inv);
    *reinterpret_cast<uint4*>(outm + (size_t)v * D + ((t & 15) << 3)) =
        *reinterpret_cast<uint4*>(o);
}

// ---------- MFMA GEMM, LDS-staged frag-major B ----------
template <typename OutT, bool DUAL, bool SELFF32>
__global__ __launch_bounds__(512) void sage_mfma_kernel(
    const ushort* __restrict__ Ab, const void* __restrict__ Sb,
    const ushort* __restrict__ Wf, const float* __restrict__ bias,
    OutT* __restrict__ out, unsigned char* __restrict__ fq, int N) {
    __shared__ uint4 ldsB[4096];  // 64 KB
    const int t = threadIdx.x;
    {
        const uint4* g = reinterpret_cast<const uint4*>(Wf);
#pragma unroll
        for (int i = 0; i < 8; ++i) ldsB[t + i * 512] = g[t + i * 512];
    }
    __syncthreads();

    const int lane = t & 63, w = t >> 6;
    const int lm = lane & 15;
    const int ksub = (lane >> 4) * 8;
    const int mbase = blockIdx.x * 128 + w * 16;

    int r0 = mbase + lm;
    if (r0 >= N) r0 = N - 1;

    f32x4 acc[8];
#pragma unroll
    for (int j = 0; j < 8; ++j) {
        float bv = bias[j * 16 + lm];
        acc[j] = {bv, bv, bv, bv};
    }

    const ushort* A0 = Ab + (size_t)r0 * D + ksub;
    const ushort* lB = reinterpret_cast<const ushort*>(ldsB) + lane * 8;

#pragma unroll
    for (int s = 0; s < 8; ++s) {
        bf16x8 a;
        if (s < 4) {
            a = *reinterpret_cast<const bf16x8*>(A0 + s * 32);
        } else if constexpr (SELFF32) {
            const float* S0 = (const float*)Sb + (size_t)r0 * D + (s - 4) * 32 + ksub;
            float4 v0 = *reinterpret_cast<const float4*>(S0);
            float4 v1 = *reinterpret_cast<const float4*>(S0 + 4);
            __hip_bfloat16 o[8];
            o[0] = __float2bfloat16(v0.x); o[1] = __float2bfloat16(v0.y);
            o[2] = __float2bfloat16(v0.z); o[3] = __float2bfloat16(v0.w);
            o[4] = __float2bfloat16(v1.x); o[5] = __float2bfloat16(v1.y);
            o[6] = __float2bfloat16(v1.z); o[7] = __float2bfloat16(v1.w);
            a = *reinterpret_cast<bf16x8*>(o);
        } else {
            const ushort* S0 = (const ushort*)Sb + (size_t)r0 * D + ksub;
            a = *reinterpret_cast<const bf16x8*>(S0 + (s - 4) * 32);
        }
#pragma unroll
        for (int j = 0; j < 8; ++j) {
            bf16x8 b = *reinterpret_cast<const bf16x8*>(lB + (j * 8 + s) * 512);
            acc[j] = __builtin_amdgcn_mfma_f32_16x16x32_bf16(a, b, acc[j], 0, 0, 0);
        }
    }

    const int rr = (lane >> 4) * 4;
#pragma unroll
    for (int r = 0; r < 4; ++r) {
        int row = mbase + rr + r;
        if (row < N) {
#pragma unroll
            for (int j = 0; j < 8; ++j) {
                float val = acc[j][r];
                if constexpr (sizeof(OutT) == 2)
                    out[(size_t)row * D + j * 16 + lm] = __float2bfloat16(val);
                else
                    out[(size_t)row * D + j * 16 + lm] = val;
                if constexpr (DUAL) {
                    int pk = __builtin_amdgcn_cvt_pk_fp8_f32(val, val, 0, false);
                    fq[(size_t)row * D + j * 16 + lm] = (unsigned char)(pk & 0xff);
                }
            }
        }
    }
}

extern "C" void kernel_launch(void* const* d_in, const int* in_sizes, int n_in,
                              void* d_out, int out_size, void* d_ws, size_t ws_size,
                              hipStream_t stream) {
    const float* x   = (const float*)d_in[0];
    const void*  ei  = d_in[1];
    const float* Wl1 = (const float*)d_in[2];
    const float* Wr1 = (const float*)d_in[3];
    const float* b1  = (const float*)d_in[4];
    const float* Wl2 = (const float*)d_in[5];
    const float* Wr2 = (const float*)d_in[6];
    const float* b2  = (const float*)d_in[7];
    float* out = (float*)d_out;

    const int N = in_sizes[0] / D;
    const int E = in_sizes[1] / 2;
    const long long ND = (long long)N * D;

    // bucket shift: keep NB <= 512 (N=100000 -> SH=8, NB=391)
    int SH = 8;
    while (((N + (1 << SH) - 1) >> SH) > 512) ++SH;
    const int NB = (N + (1 << SH) - 1) >> SH;
    const int NBLK = (E + TE - 1) / TE;
    const int Ntot = NB * NBLK;
    const int nb2 = (Ntot + SCAN_CHUNK - 1) / SCAN_CHUNK;  // must be <= 256

    // ws layout (bf16 = ushort)
    ushort* meanb = (ushort*)d_ws;                      // N*D
    ushort* h1b   = meanb + ND;                         // N*D
    ushort* Wf1   = h1b + ND;                           // 4096*8
    ushort* Wf2   = Wf1 + 32768;                        // 4096*8
    int*    rs    = (int*)(Wf2 + 32768);                // N
    int*    col   = rs + N;                             // E
    // transient aliases (dead before their hosts are written):
    int*      histT = (int*)meanb;                      // NB*NBLK (meanb written later)
    int*      bsum  = histT + Ntot;                     // nb2
    unsigned* ebuf  = (unsigned*)h1b;                   // E packed (h1b written later)
    // d_out carve-up (both dead before GEMM2 writes out):
    //   [0, ND): xq fp8; [ND, 2*ND): h1q fp8
    unsigned char* xq  = (unsigned char*)d_out;
    unsigned char* h1q = (unsigned char*)d_out + ND;

    const int ncvt = (int)((ND / 8 + 255) / 256);

    // ---- prep: fp8 convert + frag-major weights + partition histogram ----
    prep_kernel<<<ncvt + 32 + NBLK, 256, 0, stream>>>(
        x, (unsigned*)xq, ND, ncvt, Wl1, Wr1, Wl2, Wr2,
        Wf1, Wf2, ei, E, NB, NBLK, SH, histT);

    // ---- CSR via two-level counting sort (LDS atomics only; no scan_top) ----
    scan_partial_kernel<<<nb2, 256, 0, stream>>>(histT, Ntot, bsum);
    part_scatter_kernel<<<NBLK, 256, 0, stream>>>(ei, E, NB, NBLK, SH, histT, bsum, nb2, ebuf);
    bucket_csr_kernel<<<NB, 256, 0, stream>>>(ebuf, histT, bsum, nb2, NB, NBLK, SH, E, N, rs, col);

    const int agg_grid = (N + 15) / 16;
    const int gemm_grid = (N + 127) / 128;

    // ---- layer 1: gather fp8 x -> mean; GEMM (self f32 exact) -> h1b + h1q ----
    aggregate_mean_fp8_kernel<<<agg_grid, 256, 0, stream>>>(xq, rs, col, meanb, N);
    sage_mfma_kernel<__hip_bfloat16, true, true><<<gemm_grid, 512, 0, stream>>>(
        meanb, x, Wf1, b1, (__hip_bfloat16*)h1b, h1q, N);

    // ---- layer 2: gather fp8 h1 -> mean; GEMM (self bf16) -> out f32 ----
    aggregate_mean_fp8_kernel<<<agg_grid, 256, 0, stream>>>(h1q, rs, col, meanb, N);
    sage_mfma_kernel<float, false, false><<<gemm_grid, 512, 0, stream>>>(
        meanb, h1b, Wf2, b2, out, nullptr, N);
}